// Round 1
// baseline (646.218 us; speedup 1.0000x reference)
//
#include <hip/hip_runtime.h>
#include <hip/hip_bf16.h>

// Problem constants
#define NN 4096
#define FIN 512
#define HID 256
#define NH 4
#define DD 64
#define NCLS 64

// ---------------------------------------------------------------------------
// Simple tiled f32 GEMM: C[M,N] = A[M,K] * B[K,N], all row-major.
// 64x64 tile per block, 256 threads, 4x4 per thread, K-step 16.
// ---------------------------------------------------------------------------
__global__ __launch_bounds__(256) void gemm_f32(const float* __restrict__ A,
                                                const float* __restrict__ B,
                                                float* __restrict__ C,
                                                int M, int K, int N) {
    __shared__ __align__(16) float As[16 * 64];  // As[k][m]
    __shared__ __align__(16) float Bs[16 * 64];  // Bs[k][n]
    const int tid = threadIdx.x;
    const int m0 = blockIdx.y * 64, n0 = blockIdx.x * 64;
    const int tx = tid & 15, ty = tid >> 4;
    const int arow = tid >> 2, ak4 = tid & 3;
    const int brow = tid >> 4, bc4 = tid & 15;

    float acc[4][4] = {};
    for (int k0 = 0; k0 < K; k0 += 16) {
        __syncthreads();
        float4 av = *(const float4*)&A[(m0 + arow) * K + k0 + ak4 * 4];
        As[(ak4 * 4 + 0) * 64 + arow] = av.x;
        As[(ak4 * 4 + 1) * 64 + arow] = av.y;
        As[(ak4 * 4 + 2) * 64 + arow] = av.z;
        As[(ak4 * 4 + 3) * 64 + arow] = av.w;
        *(float4*)&Bs[brow * 64 + bc4 * 4] =
            *(const float4*)&B[(k0 + brow) * N + n0 + bc4 * 4];
        __syncthreads();
#pragma unroll
        for (int kk = 0; kk < 16; ++kk) {
            float4 a = *(const float4*)&As[kk * 64 + ty * 4];
            float4 b = *(const float4*)&Bs[kk * 64 + tx * 4];
            acc[0][0] += a.x * b.x; acc[0][1] += a.x * b.y; acc[0][2] += a.x * b.z; acc[0][3] += a.x * b.w;
            acc[1][0] += a.y * b.x; acc[1][1] += a.y * b.y; acc[1][2] += a.y * b.z; acc[1][3] += a.y * b.w;
            acc[2][0] += a.z * b.x; acc[2][1] += a.z * b.y; acc[2][2] += a.z * b.z; acc[2][3] += a.z * b.w;
            acc[3][0] += a.w * b.x; acc[3][1] += a.w * b.y; acc[3][2] += a.w * b.z; acc[3][3] += a.w * b.w;
        }
    }
#pragma unroll
    for (int i = 0; i < 4; ++i) {
        float4 o = make_float4(acc[i][0], acc[i][1], acc[i][2], acc[i][3]);
        *(float4*)&C[(m0 + ty * 4 + i) * N + n0 + tx * 4] = o;
    }
}

// ---------------------------------------------------------------------------
// Score kernel: s_src[h,n] = sum_d Hsrc[n, h*64+d] * a_src[h,d]  (same for dst)
// One wave per (n,h) pair; 4 waves per block.
// ---------------------------------------------------------------------------
template <int H>
__global__ __launch_bounds__(256) void score_kernel(const float* __restrict__ Hsrc,
                                                    const float* __restrict__ a_src,
                                                    const float* __restrict__ a_dst,
                                                    float* __restrict__ s_src,
                                                    float* __restrict__ s_dst) {
    constexpr int C = H * DD;
    const int p = blockIdx.x * 4 + (threadIdx.x >> 6);
    const int lane = threadIdx.x & 63;
    const int n = p / H, h = p % H;
    float v = Hsrc[n * C + h * DD + lane];
    float vs = v * a_src[h * DD + lane];
    float vd = v * a_dst[h * DD + lane];
#pragma unroll
    for (int off = 32; off >= 1; off >>= 1) {
        vs += __shfl_xor(vs, off, 64);
        vd += __shfl_xor(vd, off, 64);
    }
    if (lane == 0) {
        s_src[h * NN + n] = vs;
        s_dst[h * NN + n] = vd;
    }
}

// ---------------------------------------------------------------------------
// Fused masked-softmax attention aggregate.
//   Out[i, h*64+d] = (1/l_i_h) * sum_j w(i,j,h) * Hsrc[j, h*64+d]
//   w = (A[i,j]>0) ? exp(lrelu(s_src[i,h]+s_dst[j,h])) : 0 ; l = sum_j w
// No max-subtraction (scores are bounded small); partial sums combine freely.
// Block: 256 threads = 4 waves, BI=8 destination rows.
//  Layer1 (H=4): each wave owns one head, all waves share j-slice [0,32).
//  Layer2 (H=1): all waves head 0, each wave owns a 32-wide j-slice of a
//                128-row staged tile.  Cross-wave combine at the end.
// ---------------------------------------------------------------------------
template <int H, bool DO_ELU>
__global__ __launch_bounds__(256) void attn_kernel(const float* __restrict__ Hsrc,
                                                   const int* __restrict__ Adj,
                                                   const float* __restrict__ s_src,
                                                   const float* __restrict__ s_dst,
                                                   float* __restrict__ Out) {
    constexpr int C = H * DD;       // feature width (256 or 64)
    constexpr int NW = 4;           // waves per block
    constexpr int WPH = NW / H;     // waves per head (1 or 4)
    constexpr int TS = 32;          // j-slice width per wave
    constexpr int SJ = WPH * TS;    // staged j rows (32 or 128)
    constexpr int BI = 8;           // destination rows per block

    __shared__ __align__(16) float ht[SJ * C];          // 32 KB staged H tile
    __shared__ __align__(16) float w_sh[NW * BI * TS];  // 4 KB weights
    __shared__ int A_sh[BI * SJ];
    __shared__ float l_sh[NW * BI];

    const int tid = threadIdx.x;
    const int lane = tid & 63;
    const int q = tid >> 6;               // wave id
    const int hh = q / WPH;               // head of this wave
    const int ts = (q % WPH) * TS;        // wave's j-slice offset within tile
    const int i0 = blockIdx.x * BI;
    const int d = lane;                   // aggregation column
    const int tt = lane & 31;             // w-compute column
    const int iihalf = (lane >> 5) * (BI / 2);

    float ssrc_r[BI / 2];
#pragma unroll
    for (int r = 0; r < BI / 2; ++r)
        ssrc_r[r] = s_src[hh * NN + i0 + iihalf + r];

    float acc[BI];
    float lpart[BI / 2];
#pragma unroll
    for (int ii = 0; ii < BI; ++ii) acc[ii] = 0.f;
#pragma unroll
    for (int r = 0; r < BI / 2; ++r) lpart[r] = 0.f;

    for (int j0 = 0; j0 < NN; j0 += SJ) {
        __syncthreads();  // previous iteration's reads done before restage
        // stage H tile: SJ*C floats, coalesced float4
        constexpr int NV = SJ * C / 4;  // 2048
#pragma unroll
        for (int k = 0; k < NV / 256; ++k) {
            int idx = tid + k * 256;
            int t = idx / (C / 4);
            int c4 = idx % (C / 4);
            *(float4*)&ht[t * C + c4 * 4] =
                *(const float4*)&Hsrc[(j0 + t) * C + c4 * 4];
        }
        // stage adjacency tile
#pragma unroll
        for (int k = 0; k < (BI * SJ + 255) / 256; ++k) {
            int idx = tid + k * 256;
            if (idx < BI * SJ) {
                int ii = idx / SJ, t = idx % SJ;
                A_sh[idx] = Adj[(i0 + ii) * NN + j0 + t];
            }
        }
        __syncthreads();

        // compute unnormalized weights for this wave's slice
        const int j = j0 + ts + tt;
        const float sd = s_dst[hh * NN + j];
#pragma unroll
        for (int r = 0; r < BI / 2; ++r) {
            int ii = iihalf + r;
            float e = ssrc_r[r] + sd;
            e = (e >= 0.f) ? e : 0.2f * e;
            float w = (A_sh[ii * SJ + ts + tt] > 0) ? __expf(e) : 0.f;
            w_sh[(q * BI + ii) * TS + tt] = w;
            lpart[r] += w;
        }
        // w_sh slice is private to this wave; no barrier needed (lgkmcnt only)

        // aggregate: acc[ii] += sum_t w[ii][t] * ht[t][hh*64+d]
#pragma unroll
        for (int t4 = 0; t4 < TS / 4; ++t4) {
            const float* hp = &ht[(ts + t4 * 4) * C + hh * DD + d];
            float h0 = hp[0 * C], h1 = hp[1 * C], h2 = hp[2 * C], h3 = hp[3 * C];
#pragma unroll
            for (int ii = 0; ii < BI; ++ii) {
                float4 w4 = *(const float4*)&w_sh[(q * BI + ii) * TS + t4 * 4];
                acc[ii] += w4.x * h0 + w4.y * h1 + w4.z * h2 + w4.w * h3;
            }
        }
    }

    __syncthreads();  // all ht reads done; reuse ht as acc exchange buffer
    float* accx = ht;  // [NW][BI][64]
#pragma unroll
    for (int ii = 0; ii < BI; ++ii) accx[(q * BI + ii) * 64 + d] = acc[ii];
    // reduce lpart within each 32-lane half
#pragma unroll
    for (int r = 0; r < BI / 2; ++r) {
        float s = lpart[r];
#pragma unroll
        for (int off = 16; off >= 1; off >>= 1) s += __shfl_xor(s, off, 64);
        if (tt == 0) l_sh[q * BI + iihalf + r] = s;
    }
    __syncthreads();

    // combine partials across waves-per-head, normalize, activation, store
    for (int e = tid; e < BI * C; e += 256) {
        int ii = e / C, c = e % C;
        int hx = c / DD, dd = c % DD;
        float num = 0.f, den = 0.f;
#pragma unroll
        for (int w = 0; w < WPH; ++w) {
            int qq = hx * WPH + w;
            num += accx[(qq * BI + ii) * 64 + dd];
            den += l_sh[qq * BI + ii];
        }
        float o = num / den;
        if (DO_ELU) o = (o > 0.f) ? o : (__expf(o) - 1.f);
        Out[(i0 + ii) * C + c] = o;
    }
}

// ---------------------------------------------------------------------------
extern "C" void kernel_launch(void* const* d_in, const int* in_sizes, int n_in,
                              void* d_out, int out_size, void* d_ws, size_t ws_size,
                              hipStream_t stream) {
    const float* x      = (const float*)d_in[0];  // [4096,512]
    const int*   Adj    = (const int*)d_in[1];    // [4096,4096]
    const float* W1     = (const float*)d_in[2];  // [512,256]
    const float* a1_src = (const float*)d_in[3];  // [4,64]
    const float* a1_dst = (const float*)d_in[4];  // [4,64]
    const float* W2     = (const float*)d_in[5];  // [256,64]
    const float* a2_src = (const float*)d_in[6];  // [1,64]
    const float* a2_dst = (const float*)d_in[7];  // [1,64]
    float* out = (float*)d_out;                   // [4096,64]

    float* ws = (float*)d_ws;
    float* H1    = ws;                       // 4096*256
    float* h1e   = ws + 1048576;             // 4096*256
    float* H2    = ws + 2097152;             // 4096*64
    float* s1s   = ws + 2359296;             // 4*4096
    float* s1d   = ws + 2375680;             // 4*4096
    float* s2s   = ws + 2392064;             // 4096
    float* s2d   = ws + 2396160;             // 4096

    // Layer 1
    gemm_f32<<<dim3(HID / 64, NN / 64), 256, 0, stream>>>(x, W1, H1, NN, FIN, HID);
    score_kernel<NH><<<dim3(NN * NH / 4), 256, 0, stream>>>(H1, a1_src, a1_dst, s1s, s1d);
    attn_kernel<NH, true><<<dim3(NN / 8), 256, 0, stream>>>(H1, Adj, s1s, s1d, h1e);

    // Layer 2
    gemm_f32<<<dim3(NCLS / 64, NN / 64), 256, 0, stream>>>(h1e, W2, H2, NN, HID, NCLS);
    score_kernel<1><<<dim3(NN / 4), 256, 0, stream>>>(H2, a2_src, a2_dst, s2s, s2d);
    attn_kernel<1, false><<<dim3(NN / 8), 256, 0, stream>>>(H2, Adj, s2s, s2d, out);
}

// Round 6
// 284.371 us; speedup vs baseline: 2.2724x; 2.2724x over previous
//
#include <hip/hip_runtime.h>
#include <hip/hip_bf16.h>

// Problem constants
#define NN 4096
#define FIN 512
#define HID 256
#define NH 4
#define DD 64
#define NCLS 64

typedef short bf16x8 __attribute__((ext_vector_type(8)));
typedef float f32x4 __attribute__((ext_vector_type(4)));
typedef unsigned int u32x4 __attribute__((ext_vector_type(4)));

__device__ __forceinline__ unsigned fbits(float x) {
    return __builtin_bit_cast(unsigned, x);
}
__device__ __forceinline__ float fbitsf(unsigned u) {
    return __builtin_bit_cast(float, u);
}
__device__ __forceinline__ unsigned short f2bf_rne(float x) {
    unsigned u = fbits(x);
    unsigned r = (u + 0x7fffu + ((u >> 16) & 1u)) >> 16;
    return (unsigned short)r;
}

// ---------------------------------------------------------------------------
// Simple tiled f32 GEMM: C[M,N] = A[M,K] * B[K,N], all row-major.
// ---------------------------------------------------------------------------
__global__ __launch_bounds__(256) void gemm_f32(const float* __restrict__ A,
                                                const float* __restrict__ B,
                                                float* __restrict__ C,
                                                int M, int K, int N) {
    __shared__ __align__(16) float As[16 * 64];  // As[k][m]
    __shared__ __align__(16) float Bs[16 * 64];  // Bs[k][n]
    const int tid = threadIdx.x;
    const int m0 = blockIdx.y * 64, n0 = blockIdx.x * 64;
    const int tx = tid & 15, ty = tid >> 4;
    const int arow = tid >> 2, ak4 = tid & 3;
    const int brow = tid >> 4, bc4 = tid & 15;

    float acc[4][4] = {};
    for (int k0 = 0; k0 < K; k0 += 16) {
        __syncthreads();
        float4 av = *(const float4*)&A[(m0 + arow) * K + k0 + ak4 * 4];
        As[(ak4 * 4 + 0) * 64 + arow] = av.x;
        As[(ak4 * 4 + 1) * 64 + arow] = av.y;
        As[(ak4 * 4 + 2) * 64 + arow] = av.z;
        As[(ak4 * 4 + 3) * 64 + arow] = av.w;
        *(float4*)&Bs[brow * 64 + bc4 * 4] =
            *(const float4*)&B[(k0 + brow) * N + n0 + bc4 * 4];
        __syncthreads();
#pragma unroll
        for (int kk = 0; kk < 16; ++kk) {
            float4 a = *(const float4*)&As[kk * 64 + ty * 4];
            float4 b = *(const float4*)&Bs[kk * 64 + tx * 4];
            acc[0][0] += a.x * b.x; acc[0][1] += a.x * b.y; acc[0][2] += a.x * b.z; acc[0][3] += a.x * b.w;
            acc[1][0] += a.y * b.x; acc[1][1] += a.y * b.y; acc[1][2] += a.y * b.z; acc[1][3] += a.y * b.w;
            acc[2][0] += a.z * b.x; acc[2][1] += a.z * b.y; acc[2][2] += a.z * b.z; acc[2][3] += a.z * b.w;
            acc[3][0] += a.w * b.x; acc[3][1] += a.w * b.y; acc[3][2] += a.w * b.z; acc[3][3] += a.w * b.w;
        }
    }
#pragma unroll
    for (int i = 0; i < 4; ++i) {
        float4 o = make_float4(acc[i][0], acc[i][1], acc[i][2], acc[i][3]);
        *(float4*)&C[(m0 + ty * 4 + i) * N + n0 + tx * 4] = o;
    }
}

// ---------------------------------------------------------------------------
// Score kernel: s_src[h,n] = sum_d Hsrc[n, h*64+d] * a_src[h,d]
// ---------------------------------------------------------------------------
template <int H>
__global__ __launch_bounds__(256) void score_kernel(const float* __restrict__ Hsrc,
                                                    const float* __restrict__ a_src,
                                                    const float* __restrict__ a_dst,
                                                    float* __restrict__ s_src,
                                                    float* __restrict__ s_dst) {
    constexpr int C = H * DD;
    const int p = blockIdx.x * 4 + (threadIdx.x >> 6);
    const int lane = threadIdx.x & 63;
    const int n = p / H, h = p % H;
    float v = Hsrc[n * C + h * DD + lane];
    float vs = v * a_src[h * DD + lane];
    float vd = v * a_dst[h * DD + lane];
#pragma unroll
    for (int off = 32; off >= 1; off >>= 1) {
        vs += __shfl_xor(vs, off, 64);
        vd += __shfl_xor(vd, off, 64);
    }
    if (lane == 0) {
        s_src[h * NN + n] = vs;
        s_dst[h * NN + n] = vd;
    }
}

// ---------------------------------------------------------------------------
// Transpose + f32->bf16 convert:  OutT[c][r] = bf16(In[r][c]).
// ---------------------------------------------------------------------------
template <int RC>
__global__ __launch_bounds__(256) void transpose_cvt(const float* __restrict__ In,
                                                     unsigned short* __restrict__ OutT) {
    __shared__ float t[32][33];
    const int tid = threadIdx.x;
    const int r0 = blockIdx.y * 32, c0 = blockIdx.x * 32;
    const int rl = tid >> 3, cg = tid & 7;
    float4 v = *(const float4*)&In[(r0 + rl) * RC + c0 + cg * 4];
    t[rl][cg * 4 + 0] = v.x; t[rl][cg * 4 + 1] = v.y;
    t[rl][cg * 4 + 2] = v.z; t[rl][cg * 4 + 3] = v.w;
    __syncthreads();
    const int cl = tid >> 3, rg = tid & 7;
    ushort4 o;
    o.x = f2bf_rne(t[rg * 4 + 0][cl]);
    o.y = f2bf_rne(t[rg * 4 + 1][cl]);
    o.z = f2bf_rne(t[rg * 4 + 2][cl]);
    o.w = f2bf_rne(t[rg * 4 + 3][cl]);
    *(ushort4*)&OutT[(c0 + cl) * NN + r0 + rg * 4] = o;
}

// ---------------------------------------------------------------------------
// Build the w A-fragment (8 bf16) with plain C bit ops; element e of the
// fragment holds bf16_rtz(wv[e]); denominator accumulates the SAME bits.
// Logical convention: lane l supplies row (l&15), slot e supplies column
// j = (l>>4)*8 + e.  Whatever the HW actually does with this is measured
// by mfma_probe below and compensated in the epilogue.
// ---------------------------------------------------------------------------
__device__ __forceinline__ bf16x8 pack_w(const float* wv, float& lpart) {
    u32x4 au;
#pragma unroll
    for (int t = 0; t < 4; ++t) {
        unsigned lo = fbits(wv[2 * t]) >> 16;
        unsigned hi = fbits(wv[2 * t + 1]) & 0xffff0000u;
        au[t] = lo | hi;
        lpart += fbitsf(lo << 16) + fbitsf(hi);
    }
    return __builtin_bit_cast(bf16x8, au);
}

// ---------------------------------------------------------------------------
// Runtime MFMA layout probe.  Using the SAME fragment-construction paths as
// the attention kernels (pack_w for X, bf16x8 element order for Y):
//   P1: X[i][0]=i+1, Y[0][n]=1   => D[i][n]=i+1  -> logical row at (lane,reg)
//   P2: X[i][0]=1,   Y[0][n]=n+1 => D[i][n]=n+1  -> logical col at (lane,reg)
// Any consistent HW layout (D orientation, lane->row/col maps, operand
// quirks) is captured exactly; values 1..16 are bf16/f32-exact.
// ---------------------------------------------------------------------------
__global__ __launch_bounds__(64) void mfma_probe(float* __restrict__ pI,
                                                 float* __restrict__ pN) {
    const int l = threadIdx.x;
    const int quad = l >> 4, m = l & 15;
    float dummy = 0.f;
    float xv[8], yv[8];
#pragma unroll
    for (int e = 0; e < 8; ++e) {
        xv[e] = (quad == 0 && e == 0) ? (float)(m + 1) : 0.f;
        yv[e] = (quad == 0 && e == 0) ? 1.f : 0.f;
    }
    bf16x8 x1 = pack_w(xv, dummy);
    bf16x8 y1 = pack_w(yv, dummy);
#pragma unroll
    for (int e = 0; e < 8; ++e) {
        xv[e] = (quad == 0 && e == 0) ? 1.f : 0.f;
        yv[e] = (quad == 0 && e == 0) ? (float)(m + 1) : 0.f;
    }
    bf16x8 x2 = pack_w(xv, dummy);
    bf16x8 y2 = pack_w(yv, dummy);
    f32x4 d1 = {};
    f32x4 d2 = {};
    d1 = __builtin_amdgcn_mfma_f32_16x16x32_bf16(x1, y1, d1, 0, 0, 0);
    d2 = __builtin_amdgcn_mfma_f32_16x16x32_bf16(x2, y2, d2, 0, 0, 0);
#pragma unroll
    for (int r = 0; r < 4; ++r) {
        pI[l * 4 + r] = d1[r] - 1.f;
        pN[l * 4 + r] = d2[r] - 1.f;
    }
}

__device__ __forceinline__ void load_probe(const float* pI, const float* pN,
                                           int lane, int* pi, int* pn) {
    float4 a = *(const float4*)&pI[lane * 4];
    float4 b = *(const float4*)&pN[lane * 4];
    float av[4] = {a.x, a.y, a.z, a.w};
    float bv[4] = {b.x, b.y, b.z, b.w};
#pragma unroll
    for (int r = 0; r < 4; ++r) {
        int x = (int)av[r];
        int y = (int)bv[r];
        pi[r] = min(15, max(0, x));
        pn[r] = min(15, max(0, y));
    }
}

// ---------------------------------------------------------------------------
// MFMA attention, layer 1 (H=4).  A = generated w (logical row l&15, col
// quad*8+e), B = H fragments from HT (logical col l&15, k quad*8+e).
// Output placement & denominator use the probe-measured (pi,pn).
// ---------------------------------------------------------------------------
__global__ __launch_bounds__(256) void attn_mfma_l1(
    const unsigned short* __restrict__ HT,  // [256][4096] bf16
    const int* __restrict__ Adj,
    const float* __restrict__ ss,           // [4][4096]
    const float* __restrict__ sd,           // [4][4096]
    const float* __restrict__ pI, const float* __restrict__ pN,
    float* __restrict__ Out)                // [4096][256], ELU applied
{
    const int tid = threadIdx.x;
    const int lane = tid & 63;
    const int hh = tid >> 6;
    const int m = lane & 15;
    const int quad = lane >> 4;
    const int i0 = blockIdx.x * 16;

    int pi[4], pn[4];
    load_probe(pI, pN, lane, pi, pn);

    const float ss_m = ss[hh * NN + i0 + m];
    const long arow = (long)(i0 + m) * NN;
    const unsigned short* htb = HT + (size_t)(hh * 64) * NN;

    f32x4 acc[4] = {};
    float lpart = 0.f;

#pragma unroll 2
    for (int j0 = 0; j0 < NN; j0 += 32) {
        const int kb = j0 + quad * 8;
        int4 adj0 = *(const int4*)&Adj[arow + kb];
        int4 adj1 = *(const int4*)&Adj[arow + kb + 4];
        float4 sd0 = *(const float4*)&sd[hh * NN + kb];
        float4 sd1 = *(const float4*)&sd[hh * NN + kb + 4];
        bf16x8 b[4];
#pragma unroll
        for (int nt = 0; nt < 4; ++nt)
            b[nt] = *(const bf16x8*)&htb[(size_t)(nt * 16 + m) * NN + kb];

        float sdv[8] = {sd0.x, sd0.y, sd0.z, sd0.w, sd1.x, sd1.y, sd1.z, sd1.w};
        int adv[8] = {adj0.x, adj0.y, adj0.z, adj0.w, adj1.x, adj1.y, adj1.z, adj1.w};
        float wv[8];
#pragma unroll
        for (int t = 0; t < 8; ++t) {
            float e = ss_m + sdv[t];
            e = fmaxf(e, 0.2f * e);
            float ex = __expf(e);
            wv[t] = (adv[t] > 0) ? ex : 0.f;
        }
        bf16x8 av = pack_w(wv, lpart);
#pragma unroll
        for (int nt = 0; nt < 4; ++nt)
            acc[nt] = __builtin_amdgcn_mfma_f32_16x16x32_bf16(av, b[nt], acc[nt], 0, 0, 0);
    }

    // lpart(l) = L[l&15] by construction (layout-independent).
    lpart += __shfl_xor(lpart, 16, 64);
    lpart += __shfl_xor(lpart, 32, 64);
    float lrowv[4];
#pragma unroll
    for (int r = 0; r < 4; ++r) lrowv[r] = __shfl(lpart, pi[r], 64);

#pragma unroll
    for (int nt = 0; nt < 4; ++nt) {
#pragma unroll
        for (int r = 0; r < 4; ++r) {
            float o = acc[nt][r] / lrowv[r];
            o = (o > 0.f) ? o : (__expf(o) - 1.f);
            Out[(size_t)(i0 + pi[r]) * HID + hh * 64 + nt * 16 + pn[r]] = o;
        }
    }
}

// ---------------------------------------------------------------------------
// MFMA attention, layer 2 (H=1). 4 waves split the j-range; LDS combine.
// ---------------------------------------------------------------------------
__global__ __launch_bounds__(256) void attn_mfma_l2(
    const unsigned short* __restrict__ HT,  // [64][4096] bf16
    const int* __restrict__ Adj,
    const float* __restrict__ ss, const float* __restrict__ sd,
    const float* __restrict__ pI, const float* __restrict__ pN,
    float* __restrict__ Out)                // [4096][64]
{
    __shared__ float accx[4][16][64];
    __shared__ float lx[4][16];

    const int tid = threadIdx.x;
    const int lane = tid & 63;
    const int q = tid >> 6;
    const int m = lane & 15;
    const int quad = lane >> 4;
    const int i0 = blockIdx.x * 16;

    int pi[4], pn[4];
    load_probe(pI, pN, lane, pi, pn);

    const float ss_m = ss[i0 + m];
    const long arow = (long)(i0 + m) * NN;

    f32x4 acc[4] = {};
    float lpart = 0.f;

#pragma unroll 2
    for (int j0 = q * 32; j0 < NN; j0 += 128) {
        const int kb = j0 + quad * 8;
        int4 adj0 = *(const int4*)&Adj[arow + kb];
        int4 adj1 = *(const int4*)&Adj[arow + kb + 4];
        float4 sd0 = *(const float4*)&sd[kb];
        float4 sd1 = *(const float4*)&sd[kb + 4];
        bf16x8 b[4];
#pragma unroll
        for (int nt = 0; nt < 4; ++nt)
            b[nt] = *(const bf16x8*)&HT[(size_t)(nt * 16 + m) * NN + kb];

        float sdv[8] = {sd0.x, sd0.y, sd0.z, sd0.w, sd1.x, sd1.y, sd1.z, sd1.w};
        int adv[8] = {adj0.x, adj0.y, adj0.z, adj0.w, adj1.x, adj1.y, adj1.z, adj1.w};
        float wv[8];
#pragma unroll
        for (int t = 0; t < 8; ++t) {
            float e = ss_m + sdv[t];
            e = fmaxf(e, 0.2f * e);
            float ex = __expf(e);
            wv[t] = (adv[t] > 0) ? ex : 0.f;
        }
        bf16x8 av = pack_w(wv, lpart);
#pragma unroll
        for (int nt = 0; nt < 4; ++nt)
            acc[nt] = __builtin_amdgcn_mfma_f32_16x16x32_bf16(av, b[nt], acc[nt], 0, 0, 0);
    }

    // wave-local L_q[l&15] per lane
    lpart += __shfl_xor(lpart, 16, 64);
    lpart += __shfl_xor(lpart, 32, 64);
    if (quad == 0) lx[q][m] = lpart;
#pragma unroll
    for (int nt = 0; nt < 4; ++nt) {
#pragma unroll
        for (int r = 0; r < 4; ++r)
            accx[q][pi[r]][nt * 16 + pn[r]] = acc[nt][r];
    }
    __syncthreads();

#pragma unroll
    for (int e = 0; e < 4; ++e) {
        int idx = tid + e * 256;
        int row = idx >> 6, col = idx & 63;
        float num = accx[0][row][col] + accx[1][row][col] +
                    accx[2][row][col] + accx[3][row][col];
        float den = lx[0][row] + lx[1][row] + lx[2][row] + lx[3][row];
        Out[(size_t)(i0 + row) * NCLS + col] = num / den;
    }
}

// ---------------------------------------------------------------------------
extern "C" void kernel_launch(void* const* d_in, const int* in_sizes, int n_in,
                              void* d_out, int out_size, void* d_ws, size_t ws_size,
                              hipStream_t stream) {
    const float* x      = (const float*)d_in[0];
    const int*   Adj    = (const int*)d_in[1];
    const float* W1     = (const float*)d_in[2];
    const float* a1_src = (const float*)d_in[3];
    const float* a1_dst = (const float*)d_in[4];
    const float* W2     = (const float*)d_in[5];
    const float* a2_src = (const float*)d_in[6];
    const float* a2_dst = (const float*)d_in[7];
    float* out = (float*)d_out;

    float* ws = (float*)d_ws;
    float* buf0 = ws;                                   // H1, then h1e  (1M f)
    float* buf1 = ws + 1048576;                         // H2            (256K f)
    unsigned short* bufT = (unsigned short*)(ws + 1310720);  // HT1/HT2 (1M us)
    float* s1s = ws + 1835008;
    float* s1d = ws + 1851392;
    float* s2s = ws + 1867776;
    float* s2d = ws + 1871872;
    float* prI = ws + 1875968;   // 256 floats
    float* prN = ws + 1876224;   // 256 floats

    // Measure the actual MFMA layout for this toolchain/HW
    mfma_probe<<<dim3(1), 64, 0, stream>>>(prI, prN);

    // Layer 1
    gemm_f32<<<dim3(HID / 64, NN / 64), 256, 0, stream>>>(x, W1, buf0, NN, FIN, HID);
    score_kernel<NH><<<dim3(NN * NH / 4), 256, 0, stream>>>(buf0, a1_src, a1_dst, s1s, s1d);
    transpose_cvt<HID><<<dim3(HID / 32, NN / 32), 256, 0, stream>>>(buf0, bufT);
    attn_mfma_l1<<<dim3(NN / 16), 256, 0, stream>>>(bufT, Adj, s1s, s1d, prI, prN, buf0);

    // Layer 2
    gemm_f32<<<dim3(NCLS / 64, NN / 64), 256, 0, stream>>>(buf0, W2, buf1, NN, HID, NCLS);
    score_kernel<1><<<dim3(NN / 4), 256, 0, stream>>>(buf1, a2_src, a2_dst, s2s, s2d);
    transpose_cvt<NCLS><<<dim3(NCLS / 32, NN / 32), 256, 0, stream>>>(buf1, bufT);
    attn_mfma_l2<<<dim3(NN / 16), 256, 0, stream>>>(bufT, Adj, s2s, s2d, prI, prN, out);
}

// Round 7
// 250.913 us; speedup vs baseline: 2.5755x; 1.1333x over previous
//
#include <hip/hip_runtime.h>
#include <hip/hip_bf16.h>

// Problem constants
#define NN 4096
#define FIN 512
#define HID 256
#define NH 4
#define DD 64
#define NCLS 64

typedef short bf16x8 __attribute__((ext_vector_type(8)));
typedef float f32x4 __attribute__((ext_vector_type(4)));
typedef unsigned int u32x4 __attribute__((ext_vector_type(4)));

__device__ __forceinline__ unsigned fbits(float x) {
    return __builtin_bit_cast(unsigned, x);
}
__device__ __forceinline__ float fbitsf(unsigned u) {
    return __builtin_bit_cast(float, u);
}
__device__ __forceinline__ unsigned short f2bf_rne(float x) {
    unsigned u = fbits(x);
    unsigned r = (u + 0x7fffu + ((u >> 16) & 1u)) >> 16;
    return (unsigned short)r;
}

// ---------------------------------------------------------------------------
// pack_w: build bf16x8 A-fragment from 8 f32 (truncate), accumulate the SAME
// rounded values into lpart (denominator consistency). Verified in R6.
// ---------------------------------------------------------------------------
__device__ __forceinline__ bf16x8 pack_w(const float* wv, float& lpart) {
    u32x4 au;
#pragma unroll
    for (int t = 0; t < 4; ++t) {
        unsigned lo = fbits(wv[2 * t]) >> 16;
        unsigned hi = fbits(wv[2 * t + 1]) & 0xffff0000u;
        au[t] = lo | hi;
        lpart += fbitsf(lo << 16) + fbitsf(hi);
    }
    return __builtin_bit_cast(bf16x8, au);
}

// ---------------------------------------------------------------------------
// Runtime MFMA layout probe (verified R6): recovers logical (row,col) at
// each (lane, reg) of D for our fragment-construction convention.
// ---------------------------------------------------------------------------
__global__ __launch_bounds__(64) void mfma_probe(float* __restrict__ pI,
                                                 float* __restrict__ pN) {
    const int l = threadIdx.x;
    const int quad = l >> 4, m = l & 15;
    float dummy = 0.f;
    float xv[8], yv[8];
#pragma unroll
    for (int e = 0; e < 8; ++e) {
        xv[e] = (quad == 0 && e == 0) ? (float)(m + 1) : 0.f;
        yv[e] = (quad == 0 && e == 0) ? 1.f : 0.f;
    }
    bf16x8 x1 = pack_w(xv, dummy);
    bf16x8 y1 = pack_w(yv, dummy);
#pragma unroll
    for (int e = 0; e < 8; ++e) {
        xv[e] = (quad == 0 && e == 0) ? 1.f : 0.f;
        yv[e] = (quad == 0 && e == 0) ? (float)(m + 1) : 0.f;
    }
    bf16x8 x2 = pack_w(xv, dummy);
    bf16x8 y2 = pack_w(yv, dummy);
    f32x4 d1 = {};
    f32x4 d2 = {};
    d1 = __builtin_amdgcn_mfma_f32_16x16x32_bf16(x1, y1, d1, 0, 0, 0);
    d2 = __builtin_amdgcn_mfma_f32_16x16x32_bf16(x2, y2, d2, 0, 0, 0);
#pragma unroll
    for (int r = 0; r < 4; ++r) {
        pI[l * 4 + r] = d1[r] - 1.f;
        pN[l * 4 + r] = d2[r] - 1.f;
    }
}

__device__ __forceinline__ void load_probe(const float* pI, const float* pN,
                                           int lane, int* pi, int* pn) {
    float4 a = *(const float4*)&pI[lane * 4];
    float4 b = *(const float4*)&pN[lane * 4];
    float av[4] = {a.x, a.y, a.z, a.w};
    float bv[4] = {b.x, b.y, b.z, b.w};
#pragma unroll
    for (int r = 0; r < 4; ++r) {
        pi[r] = min(15, max(0, (int)av[r]));
        pn[r] = min(15, max(0, (int)bv[r]));
    }
}

// ---------------------------------------------------------------------------
// Adjacency -> bitmask: bit (j&31) of Adjb[i*128 + j/32] = Adj[i][j]>0.
// Wave-cooperative via __ballot; fully coalesced streaming read.
// ---------------------------------------------------------------------------
__global__ __launch_bounds__(256) void adj_bitmask(const int* __restrict__ Adj,
                                                   unsigned* __restrict__ Adjb) {
    const size_t gid = (size_t)blockIdx.x * 256 + threadIdx.x;
    const int lane = threadIdx.x & 63;
    int v = Adj[gid];
    unsigned long long b = __ballot(v > 0);
    if ((lane & 31) == 0)
        Adjb[gid >> 5] = (unsigned)(lane ? (b >> 32) : b);
}

// ---------------------------------------------------------------------------
// Generic transpose + f32->bf16:  In[R][C] f32 -> OutT[C][R] bf16.
// ---------------------------------------------------------------------------
template <int R, int C>
__global__ __launch_bounds__(256) void transpose_cvt(const float* __restrict__ In,
                                                     unsigned short* __restrict__ OutT) {
    __shared__ float t[32][33];
    const int tid = threadIdx.x;
    const int r0 = blockIdx.y * 32, c0 = blockIdx.x * 32;
    const int rl = tid >> 3, cg = tid & 7;
    float4 v = *(const float4*)&In[(size_t)(r0 + rl) * C + c0 + cg * 4];
    t[rl][cg * 4 + 0] = v.x; t[rl][cg * 4 + 1] = v.y;
    t[rl][cg * 4 + 2] = v.z; t[rl][cg * 4 + 3] = v.w;
    __syncthreads();
    const int cl = tid >> 3, rg = tid & 7;
    ushort4 o;
    o.x = f2bf_rne(t[rg * 4 + 0][cl]);
    o.y = f2bf_rne(t[rg * 4 + 1][cl]);
    o.z = f2bf_rne(t[rg * 4 + 2][cl]);
    o.w = f2bf_rne(t[rg * 4 + 3][cl]);
    *(ushort4*)&OutT[(size_t)(c0 + cl) * R + r0 + rg * 4] = o;
}

// ---------------------------------------------------------------------------
// Score kernel: s_src[h,n] = sum_d Hsrc[n, h*64+d] * a_src[h,d]  (f32 H).
// ---------------------------------------------------------------------------
template <int H>
__global__ __launch_bounds__(256) void score_kernel(const float* __restrict__ Hsrc,
                                                    const float* __restrict__ a_src,
                                                    const float* __restrict__ a_dst,
                                                    float* __restrict__ s_src,
                                                    float* __restrict__ s_dst) {
    constexpr int C = H * DD;
    const int p = blockIdx.x * 4 + (threadIdx.x >> 6);
    const int lane = threadIdx.x & 63;
    const int n = p / H, h = p % H;
    float v = Hsrc[(size_t)n * C + h * DD + lane];
    float vs = v * a_src[h * DD + lane];
    float vd = v * a_dst[h * DD + lane];
#pragma unroll
    for (int off = 32; off >= 1; off >>= 1) {
        vs += __shfl_xor(vs, off, 64);
        vd += __shfl_xor(vd, off, 64);
    }
    if (lane == 0) {
        s_src[h * NN + n] = vs;
        s_dst[h * NN + n] = vd;
    }
}

// ---------------------------------------------------------------------------
// MFMA GEMM: C[M,N] = A[M,K] (f32 or bf16 row-major) * WT^T  (WT = [N][K] bf16).
// One wave per 16x64 output tile; probe-compensated epilogue.
// ---------------------------------------------------------------------------
template <int K, int N, bool A_BF16>
__global__ __launch_bounds__(64) void gemm_mfma(const void* __restrict__ Ap,
                                                const unsigned short* __restrict__ WT,
                                                const float* __restrict__ pI,
                                                const float* __restrict__ pN,
                                                float* __restrict__ C) {
    const int lane = threadIdx.x;
    const int m = lane & 15, quad = lane >> 4;
    const int i0 = blockIdx.y * 16, n0 = blockIdx.x * 64;
    int pi[4], pn[4];
    load_probe(pI, pN, lane, pi, pn);
    f32x4 acc[4] = {};
#pragma unroll 4
    for (int k0 = 0; k0 < K; k0 += 32) {
        const int kb = k0 + quad * 8;
        bf16x8 a;
        if (A_BF16) {
            a = *(const bf16x8*)((const unsigned short*)Ap + (size_t)(i0 + m) * K + kb);
        } else {
            const float* Af = (const float*)Ap + (size_t)(i0 + m) * K + kb;
            float4 a0 = *(const float4*)Af;
            float4 a1 = *(const float4*)(Af + 4);
            float av8[8] = {a0.x, a0.y, a0.z, a0.w, a1.x, a1.y, a1.z, a1.w};
            u32x4 au;
#pragma unroll
            for (int t = 0; t < 4; ++t) {
                unsigned lo = (unsigned)f2bf_rne(av8[2 * t]);
                unsigned hi = (unsigned)f2bf_rne(av8[2 * t + 1]) << 16;
                au[t] = lo | hi;
            }
            a = __builtin_bit_cast(bf16x8, au);
        }
        bf16x8 b[4];
#pragma unroll
        for (int nt = 0; nt < 4; ++nt)
            b[nt] = *(const bf16x8*)&WT[(size_t)(n0 + nt * 16 + m) * K + kb];
#pragma unroll
        for (int nt = 0; nt < 4; ++nt)
            acc[nt] = __builtin_amdgcn_mfma_f32_16x16x32_bf16(a, b[nt], acc[nt], 0, 0, 0);
    }
#pragma unroll
    for (int nt = 0; nt < 4; ++nt)
#pragma unroll
        for (int r = 0; r < 4; ++r)
            C[(size_t)(i0 + pi[r]) * N + n0 + nt * 16 + pn[r]] = acc[nt][r];
}

// ---------------------------------------------------------------------------
// MFMA attention, layer 1.  1024 threads = 16 waves: wave w -> head (w&3),
// j-split (w>>2) of 1024 cols.  Bitmask adjacency.  LDS cross-split combine.
// Output: bf16 row-major [4096][256] with ELU (feeds gemm2 + transpose? no —
// transpose for l2's HT comes from H2).  Grid 256.
// ---------------------------------------------------------------------------
__global__ __launch_bounds__(1024) void attn_mfma_l1(
    const unsigned short* __restrict__ HT,  // [256][4096] bf16
    const unsigned* __restrict__ Adjb,      // [4096][128] bitmask
    const float* __restrict__ ss, const float* __restrict__ sd,  // [4][4096]
    const float* __restrict__ pI, const float* __restrict__ pN,
    unsigned short* __restrict__ Outb)      // [4096][256] bf16, ELU applied
{
    __shared__ float accx[4][16][256];  // [split][row][col] 64 KB
    __shared__ float lx[4][4][16];      // [split][head][row]

    const int tid = threadIdx.x;
    const int lane = tid & 63;
    const int w = tid >> 6;
    const int hh = w & 3;
    const int sp = w >> 2;
    const int m = lane & 15;
    const int quad = lane >> 4;
    const int i0 = blockIdx.x * 16;

    int pi[4], pn[4];
    load_probe(pI, pN, lane, pi, pn);

    const float ss_m = ss[hh * NN + i0 + m];
    const unsigned* mrow = Adjb + (size_t)(i0 + m) * 128;
    const unsigned short* htb = HT + (size_t)(hh * 64) * NN;
    const float* sdh = sd + hh * NN;

    f32x4 acc[4] = {};
    float lpart = 0.f;

    for (int g = 0; g < 8; ++g) {
        const int jbase = sp * 1024 + g * 128;
        u32x4 mw = *(const u32x4*)&mrow[jbase >> 5];
#pragma unroll
        for (int s = 0; s < 4; ++s) {
            const int kb = jbase + s * 32 + quad * 8;
            const unsigned mb = (mw[s] >> (quad * 8)) & 0xffu;
            float4 sd0 = *(const float4*)&sdh[kb];
            float4 sd1 = *(const float4*)&sdh[kb + 4];
            bf16x8 b[4];
#pragma unroll
            for (int nt = 0; nt < 4; ++nt)
                b[nt] = *(const bf16x8*)&htb[(size_t)(nt * 16 + m) * NN + kb];
            float sdv[8] = {sd0.x, sd0.y, sd0.z, sd0.w, sd1.x, sd1.y, sd1.z, sd1.w};
            float wv[8];
#pragma unroll
            for (int t = 0; t < 8; ++t) {
                float e = ss_m + sdv[t];
                e = fmaxf(e, 0.2f * e);
                float ex = __expf(e);
                wv[t] = ((mb >> t) & 1u) ? ex : 0.f;
            }
            bf16x8 av = pack_w(wv, lpart);
#pragma unroll
            for (int nt = 0; nt < 4; ++nt)
                acc[nt] = __builtin_amdgcn_mfma_f32_16x16x32_bf16(av, b[nt], acc[nt], 0, 0, 0);
        }
    }

    // wave-local L[m] for this (head, split)
    lpart += __shfl_xor(lpart, 16, 64);
    lpart += __shfl_xor(lpart, 32, 64);
    if (quad == 0) lx[sp][hh][m] = lpart;
#pragma unroll
    for (int nt = 0; nt < 4; ++nt)
#pragma unroll
        for (int r = 0; r < 4; ++r)
            accx[sp][pi[r]][hh * 64 + nt * 16 + pn[r]] = acc[nt][r];
    __syncthreads();

#pragma unroll
    for (int e = 0; e < 4; ++e) {
        int idx = tid + e * 1024;
        int row = idx >> 8, col = idx & 255;
        float num = accx[0][row][col] + accx[1][row][col] +
                    accx[2][row][col] + accx[3][row][col];
        int hx = col >> 6;
        float den = lx[0][hx][row] + lx[1][hx][row] +
                    lx[2][hx][row] + lx[3][hx][row];
        float o = num / den;
        o = (o > 0.f) ? o : (__expf(o) - 1.f);
        Outb[(size_t)(i0 + row) * HID + col] = f2bf_rne(o);
    }
}

// ---------------------------------------------------------------------------
// MFMA attention, layer 2 (H=1).  16 waves = 16 j-splits of 256 cols.
// ---------------------------------------------------------------------------
__global__ __launch_bounds__(1024) void attn_mfma_l2(
    const unsigned short* __restrict__ HT,  // [64][4096] bf16
    const unsigned* __restrict__ Adjb,
    const float* __restrict__ ss, const float* __restrict__ sd,
    const float* __restrict__ pI, const float* __restrict__ pN,
    float* __restrict__ Out)                // [4096][64] f32
{
    __shared__ float accx[16][16][64];  // 64 KB
    __shared__ float lx[16][16];

    const int tid = threadIdx.x;
    const int lane = tid & 63;
    const int sp = tid >> 6;
    const int m = lane & 15;
    const int quad = lane >> 4;
    const int i0 = blockIdx.x * 16;

    int pi[4], pn[4];
    load_probe(pI, pN, lane, pi, pn);

    const float ss_m = ss[i0 + m];
    const unsigned* mrow = Adjb + (size_t)(i0 + m) * 128;

    f32x4 acc[4] = {};
    float lpart = 0.f;

#pragma unroll
    for (int g = 0; g < 2; ++g) {
        const int jbase = sp * 256 + g * 128;
        u32x4 mw = *(const u32x4*)&mrow[jbase >> 5];
#pragma unroll
        for (int s = 0; s < 4; ++s) {
            const int kb = jbase + s * 32 + quad * 8;
            const unsigned mb = (mw[s] >> (quad * 8)) & 0xffu;
            float4 sd0 = *(const float4*)&sd[kb];
            float4 sd1 = *(const float4*)&sd[kb + 4];
            bf16x8 b[4];
#pragma unroll
            for (int nt = 0; nt < 4; ++nt)
                b[nt] = *(const bf16x8*)&HT[(size_t)(nt * 16 + m) * NN + kb];
            float sdv[8] = {sd0.x, sd0.y, sd0.z, sd0.w, sd1.x, sd1.y, sd1.z, sd1.w};
            float wv[8];
#pragma unroll
            for (int t = 0; t < 8; ++t) {
                float e = ss_m + sdv[t];
                e = fmaxf(e, 0.2f * e);
                float ex = __expf(e);
                wv[t] = ((mb >> t) & 1u) ? ex : 0.f;
            }
            bf16x8 av = pack_w(wv, lpart);
#pragma unroll
            for (int nt = 0; nt < 4; ++nt)
                acc[nt] = __builtin_amdgcn_mfma_f32_16x16x32_bf16(av, b[nt], acc[nt], 0, 0, 0);
        }
    }

    lpart += __shfl_xor(lpart, 16, 64);
    lpart += __shfl_xor(lpart, 32, 64);
    if (quad == 0) lx[sp][m] = lpart;
#pragma unroll
    for (int nt = 0; nt < 4; ++nt)
#pragma unroll
        for (int r = 0; r < 4; ++r)
            accx[sp][pi[r]][nt * 16 + pn[r]] = acc[nt][r];
    __syncthreads();

    // 1024 threads cover 16x64 outputs exactly
    {
        int row = tid >> 6, col = tid & 63;
        float num = 0.f, den = 0.f;
#pragma unroll
        for (int s = 0; s < 16; ++s) {
            num += accx[s][row][col];
            den += lx[s][row];
        }
        Out[(size_t)(i0 + row) * NCLS + col] = num / den;
    }
}

// ---------------------------------------------------------------------------
extern "C" void kernel_launch(void* const* d_in, const int* in_sizes, int n_in,
                              void* d_out, int out_size, void* d_ws, size_t ws_size,
                              hipStream_t stream) {
    const float* x      = (const float*)d_in[0];
    const int*   Adj    = (const int*)d_in[1];
    const float* W1     = (const float*)d_in[2];
    const float* a1_src = (const float*)d_in[3];
    const float* a1_dst = (const float*)d_in[4];
    const float* W2     = (const float*)d_in[5];
    const float* a2_src = (const float*)d_in[6];
    const float* a2_dst = (const float*)d_in[7];
    float* out = (float*)d_out;

    float* ws = (float*)d_ws;
    // f32-unit offsets (regions reused once producers/consumers retire):
    float*          H1     = ws;                                  // [0, 1M)
    unsigned short* h1e_bf = (unsigned short*)ws;                 // [0, 512K) after H1 dead
    unsigned short* HT1    = (unsigned short*)(ws + 1048576);     // [1M, 1.5M)
    float*          H2     = ws + 1048576;                        // aliases dead HT1
    unsigned short* HT2    = (unsigned short*)(ws + 1310720);     // [1.25M, 1.375M)
    unsigned short* WT1    = (unsigned short*)(ws + 1572864);     // 64K f
    unsigned short* WT2    = (unsigned short*)(ws + 1638400);     // 8K f
    unsigned*       Adjb   = (unsigned*)(ws + 1646592);           // 512K words
    float* s1s = ws + 2170880;
    float* s1d = ws + 2187264;
    float* s2s = ws + 2203648;
    float* s2d = ws + 2207744;
    float* prI = ws + 2211840;
    float* prN = ws + 2212096;

    // Prep
    mfma_probe<<<dim3(1), 64, 0, stream>>>(prI, prN);
    adj_bitmask<<<dim3(65536), 256, 0, stream>>>(Adj, Adjb);
    transpose_cvt<FIN, HID><<<dim3(HID / 32, FIN / 32), 256, 0, stream>>>(W1, WT1);
    transpose_cvt<HID, NCLS><<<dim3(NCLS / 32, HID / 32), 256, 0, stream>>>(W2, WT2);

    // Layer 1
    gemm_mfma<FIN, HID, false><<<dim3(HID / 64, NN / 16), 64, 0, stream>>>(x, WT1, prI, prN, H1);
    score_kernel<NH><<<dim3(NN * NH / 4), 256, 0, stream>>>(H1, a1_src, a1_dst, s1s, s1d);
    transpose_cvt<NN, HID><<<dim3(HID / 32, NN / 32), 256, 0, stream>>>(H1, HT1);
    attn_mfma_l1<<<dim3(NN / 16), 1024, 0, stream>>>(HT1, Adjb, s1s, s1d, prI, prN, h1e_bf);

    // Layer 2
    gemm_mfma<HID, NCLS, true><<<dim3(NCLS / 64, NN / 16), 64, 0, stream>>>(h1e_bf, WT2, prI, prN, H2);
    score_kernel<1><<<dim3(NN / 4), 256, 0, stream>>>(H2, a2_src, a2_dst, s2s, s2d);
    transpose_cvt<NN, NCLS><<<dim3(NCLS / 32, NN / 32), 256, 0, stream>>>(H2, HT2);
    attn_mfma_l2<<<dim3(NN / 16), 1024, 0, stream>>>(HT2, Adjb, s2s, s2d, prI, prN, out);
}

// Round 8
// 245.350 us; speedup vs baseline: 2.6339x; 1.0227x over previous
//
#include <hip/hip_runtime.h>
#include <hip/hip_bf16.h>

// Problem constants
#define NN 4096
#define FIN 512
#define HID 256
#define NH 4
#define DD 64
#define NCLS 64

typedef short bf16x8 __attribute__((ext_vector_type(8)));
typedef float f32x4 __attribute__((ext_vector_type(4)));
typedef unsigned int u32x4 __attribute__((ext_vector_type(4)));

__device__ __forceinline__ unsigned fbits(float x) {
    return __builtin_bit_cast(unsigned, x);
}
__device__ __forceinline__ float fbitsf(unsigned u) {
    return __builtin_bit_cast(float, u);
}
__device__ __forceinline__ unsigned short f2bf_rne(float x) {
    unsigned u = fbits(x);
    unsigned r = (u + 0x7fffu + ((u >> 16) & 1u)) >> 16;
    return (unsigned short)r;
}

// pack 8 f32 -> bf16x8 fragment (truncate; same rounding as R6/R7-verified)
__device__ __forceinline__ bf16x8 pack_w(const float* wv) {
    u32x4 au;
#pragma unroll
    for (int t = 0; t < 4; ++t)
        au[t] = (fbits(wv[2 * t]) >> 16) | (fbits(wv[2 * t + 1]) & 0xffff0000u);
    return __builtin_bit_cast(bf16x8, au);
}

__device__ __forceinline__ bf16x8 ones_frag() {
    u32x4 au = {0x3f803f80u, 0x3f803f80u, 0x3f803f80u, 0x3f803f80u};
    return __builtin_bit_cast(bf16x8, au);
}

// ---------------------------------------------------------------------------
// Runtime MFMA layout probe (verified R6/R7).
// ---------------------------------------------------------------------------
__global__ __launch_bounds__(64) void mfma_probe(float* __restrict__ pI,
                                                 float* __restrict__ pN) {
    const int l = threadIdx.x;
    const int quad = l >> 4, m = l & 15;
    float xv[8], yv[8];
#pragma unroll
    for (int e = 0; e < 8; ++e) {
        xv[e] = (quad == 0 && e == 0) ? (float)(m + 1) : 0.f;
        yv[e] = (quad == 0 && e == 0) ? 1.f : 0.f;
    }
    bf16x8 x1 = pack_w(xv);
    bf16x8 y1 = pack_w(yv);
#pragma unroll
    for (int e = 0; e < 8; ++e) {
        xv[e] = (quad == 0 && e == 0) ? 1.f : 0.f;
        yv[e] = (quad == 0 && e == 0) ? (float)(m + 1) : 0.f;
    }
    bf16x8 x2 = pack_w(xv);
    bf16x8 y2 = pack_w(yv);
    f32x4 d1 = {};
    f32x4 d2 = {};
    d1 = __builtin_amdgcn_mfma_f32_16x16x32_bf16(x1, y1, d1, 0, 0, 0);
    d2 = __builtin_amdgcn_mfma_f32_16x16x32_bf16(x2, y2, d2, 0, 0, 0);
#pragma unroll
    for (int r = 0; r < 4; ++r) {
        pI[l * 4 + r] = d1[r] - 1.f;
        pN[l * 4 + r] = d2[r] - 1.f;
    }
}

__device__ __forceinline__ void load_probe(const float* pI, const float* pN,
                                           int lane, int* pi, int* pn) {
    float4 a = *(const float4*)&pI[lane * 4];
    float4 b = *(const float4*)&pN[lane * 4];
    float av[4] = {a.x, a.y, a.z, a.w};
    float bv[4] = {b.x, b.y, b.z, b.w};
#pragma unroll
    for (int r = 0; r < 4; ++r) {
        pi[r] = min(15, max(0, (int)av[r]));
        pn[r] = min(15, max(0, (int)bv[r]));
    }
}

// ---------------------------------------------------------------------------
// Adjacency -> bitmask (4 elems/thread, coalesced).
// ---------------------------------------------------------------------------
__global__ __launch_bounds__(256) void adj_bitmask(const int* __restrict__ Adj,
                                                   unsigned* __restrict__ Adjb) {
    const size_t base = (size_t)blockIdx.x * 1024;
    const int tid = threadIdx.x, lane = tid & 63;
#pragma unroll
    for (int c = 0; c < 4; ++c) {
        size_t gid = base + c * 256 + tid;
        int v = Adj[gid];
        unsigned long long bm = __ballot(v > 0);
        if ((lane & 31) == 0)
            Adjb[gid >> 5] = (unsigned)((lane & 32) ? (bm >> 32) : bm);
    }
}

// ---------------------------------------------------------------------------
// Transpose + f32->bf16:  In[R][C] f32 -> OutT[C][R] bf16. (weights only)
// ---------------------------------------------------------------------------
template <int R, int C>
__global__ __launch_bounds__(256) void transpose_cvt(const float* __restrict__ In,
                                                     unsigned short* __restrict__ OutT) {
    __shared__ float t[32][33];
    const int tid = threadIdx.x;
    const int r0 = blockIdx.y * 32, c0 = blockIdx.x * 32;
    const int rl = tid >> 3, cg = tid & 7;
    float4 v = *(const float4*)&In[(size_t)(r0 + rl) * C + c0 + cg * 4];
    t[rl][cg * 4 + 0] = v.x; t[rl][cg * 4 + 1] = v.y;
    t[rl][cg * 4 + 2] = v.z; t[rl][cg * 4 + 3] = v.w;
    __syncthreads();
    const int cl = tid >> 3, rg = tid & 7;
    ushort4 o;
    o.x = f2bf_rne(t[rg * 4 + 0][cl]);
    o.y = f2bf_rne(t[rg * 4 + 1][cl]);
    o.z = f2bf_rne(t[rg * 4 + 2][cl]);
    o.w = f2bf_rne(t[rg * 4 + 3][cl]);
    *(ushort4*)&OutT[(size_t)(c0 + cl) * R + r0 + rg * 4] = o;
}

// ---------------------------------------------------------------------------
// Fused GEMM head: C-tile = A[16 rows] x WT^T[64 cols of head hh], 4-wave
// k-split, then epilogue emits: HT (bf16, transposed), raw scores (src/dst),
// and E1d=exp(sd), E2d=exp(sd/5) for the exp-free attention loop.
// Grid: (heads, NN/16). Block 256 threads.
// ---------------------------------------------------------------------------
template <int K, bool ABF>
__global__ __launch_bounds__(256) void gemm_head(
    const void* __restrict__ Ap,
    const unsigned short* __restrict__ WT,      // [H*64][K] bf16
    const float* __restrict__ a_src, const float* __restrict__ a_dst,  // [H][64]
    const float* __restrict__ pI, const float* __restrict__ pN,
    unsigned short* __restrict__ HT,            // [H*64][NN] bf16
    float* __restrict__ ssr, float* __restrict__ sdr,   // [H][NN]
    float* __restrict__ E1d, float* __restrict__ E2d)   // [H][NN]
{
    __shared__ float accx[4][16][64];
    __shared__ unsigned short hbf[16][64];
    const int tid = threadIdx.x;
    const int lane = tid & 63, sp = tid >> 6;
    const int m = lane & 15, quad = lane >> 4;
    const int hh = blockIdx.x, i0 = blockIdx.y * 16;
    const int n0 = hh * 64;
    int pi[4], pn[4];
    load_probe(pI, pN, lane, pi, pn);
    f32x4 acc[4] = {};
    constexpr int KS = K / 128;
#pragma unroll
    for (int ks = 0; ks < KS; ++ks) {
        const int kb = sp * (K / 4) + ks * 32 + quad * 8;
        bf16x8 a;
        if (ABF) {
            a = *(const bf16x8*)((const unsigned short*)Ap + (size_t)(i0 + m) * K + kb);
        } else {
            const float* Af = (const float*)Ap + (size_t)(i0 + m) * K + kb;
            float4 a0 = *(const float4*)Af;
            float4 a1 = *(const float4*)(Af + 4);
            float av8[8] = {a0.x, a0.y, a0.z, a0.w, a1.x, a1.y, a1.z, a1.w};
            u32x4 au;
#pragma unroll
            for (int t = 0; t < 4; ++t) {
                unsigned lo = (unsigned)f2bf_rne(av8[2 * t]);
                unsigned hi = (unsigned)f2bf_rne(av8[2 * t + 1]) << 16;
                au[t] = lo | hi;
            }
            a = __builtin_bit_cast(bf16x8, au);
        }
        bf16x8 b[4];
#pragma unroll
        for (int nt = 0; nt < 4; ++nt)
            b[nt] = *(const bf16x8*)&WT[(size_t)(n0 + nt * 16 + m) * K + kb];
#pragma unroll
        for (int nt = 0; nt < 4; ++nt)
            acc[nt] = __builtin_amdgcn_mfma_f32_16x16x32_bf16(a, b[nt], acc[nt], 0, 0, 0);
    }
#pragma unroll
    for (int nt = 0; nt < 4; ++nt)
#pragma unroll
        for (int r = 0; r < 4; ++r)
            accx[sp][pi[r]][nt * 16 + pn[r]] = acc[nt][r];
    __syncthreads();

    const int row = tid >> 4, cg = tid & 15;
    float ps = 0.f, pd = 0.f;
#pragma unroll
    for (int c4 = 0; c4 < 4; ++c4) {
        int col = cg * 4 + c4;
        float val = accx[0][row][col] + accx[1][row][col] +
                    accx[2][row][col] + accx[3][row][col];
        ps += val * a_src[n0 + col];
        pd += val * a_dst[n0 + col];
        hbf[row][col] = f2bf_rne(val);
    }
#pragma unroll
    for (int o = 8; o >= 1; o >>= 1) {
        ps += __shfl_xor(ps, o, 64);
        pd += __shfl_xor(pd, o, 64);
    }
    if (cg == 0) {
        int node = i0 + row;
        ssr[hh * NN + node] = ps;
        sdr[hh * NN + node] = pd;
        E1d[hh * NN + node] = __expf(pd);
        E2d[hh * NN + node] = __expf(0.2f * pd);
    }
    __syncthreads();
    const int c = tid >> 2, rq = tid & 3;
    ushort4 o4;
    o4.x = hbf[rq * 4 + 0][c];
    o4.y = hbf[rq * 4 + 1][c];
    o4.z = hbf[rq * 4 + 2][c];
    o4.w = hbf[rq * 4 + 3][c];
    *(ushort4*)&HT[(size_t)(n0 + c) * NN + i0 + rq * 4] = o4;
}

// ---------------------------------------------------------------------------
// Attention layer 1: grid (NN/16, NH), 512 threads = 8 waves = 8 j-splits of
// 512 cols for ONE head.  Exp-free weights; denominator via ones-MFMA.
// ---------------------------------------------------------------------------
__global__ __launch_bounds__(512) void attn_l1(
    const unsigned short* __restrict__ HT,   // [256][4096]
    const unsigned* __restrict__ Adjb,
    const float* __restrict__ ssr, const float* __restrict__ sdr,
    const float* __restrict__ E1d, const float* __restrict__ E2d,
    const float* __restrict__ pI, const float* __restrict__ pN,
    unsigned short* __restrict__ Outb)       // [4096][256] bf16 ELU'd
{
    __shared__ float accx[8][16][64];
    __shared__ float lx[8][16];
    const int tid = threadIdx.x;
    const int lane = tid & 63, sp = tid >> 6;
    const int m = lane & 15, quad = lane >> 4;
    const int i0 = blockIdx.x * 16, hh = blockIdx.y;
    int pi[4], pn[4];
    load_probe(pI, pN, lane, pi, pn);

    const float ss_m = ssr[hh * NN + i0 + m];
    const float E1i = __expf(ss_m), E2i = __expf(0.2f * ss_m);
    const float negss = -ss_m;
    const unsigned* mrow = Adjb + (size_t)(i0 + m) * 128;
    const unsigned short* htb = HT + (size_t)(hh * 64) * NN;
    const float* sdh = sdr + hh * NN;
    const float* e1h = E1d + hh * NN;
    const float* e2h = E2d + hh * NN;
    const bf16x8 ones = ones_frag();

    f32x4 acc[4] = {};
    f32x4 accd = {};

    for (int g = 0; g < 4; ++g) {
        const int jb = sp * 512 + g * 128;
        u32x4 mw = *(const u32x4*)&mrow[jb >> 5];
#pragma unroll
        for (int s = 0; s < 4; ++s) {
            const int kb = jb + s * 32 + quad * 8;
            const unsigned mb = (mw[s] >> (quad * 8)) & 0xffu;
            float4 s0 = *(const float4*)&sdh[kb];
            float4 s1 = *(const float4*)&sdh[kb + 4];
            float4 p0 = *(const float4*)&e1h[kb];
            float4 p1 = *(const float4*)&e1h[kb + 4];
            float4 q0 = *(const float4*)&e2h[kb];
            float4 q1 = *(const float4*)&e2h[kb + 4];
            bf16x8 b[4];
#pragma unroll
            for (int nt = 0; nt < 4; ++nt)
                b[nt] = *(const bf16x8*)&htb[(size_t)(nt * 16 + m) * NN + kb];
            float sdv[8] = {s0.x, s0.y, s0.z, s0.w, s1.x, s1.y, s1.z, s1.w};
            float e1v[8] = {p0.x, p0.y, p0.z, p0.w, p1.x, p1.y, p1.z, p1.w};
            float e2v[8] = {q0.x, q0.y, q0.z, q0.w, q1.x, q1.y, q1.z, q1.w};
            float wv[8];
#pragma unroll
            for (int t = 0; t < 8; ++t) {
                bool pos = sdv[t] >= negss;
                float w = (pos ? E1i : E2i) * (pos ? e1v[t] : e2v[t]);
                wv[t] = ((mb >> t) & 1u) ? w : 0.f;
            }
            bf16x8 av = pack_w(wv);
            accd = __builtin_amdgcn_mfma_f32_16x16x32_bf16(av, ones, accd, 0, 0, 0);
#pragma unroll
            for (int nt = 0; nt < 4; ++nt)
                acc[nt] = __builtin_amdgcn_mfma_f32_16x16x32_bf16(av, b[nt], acc[nt], 0, 0, 0);
        }
    }

#pragma unroll
    for (int nt = 0; nt < 4; ++nt)
#pragma unroll
        for (int r = 0; r < 4; ++r)
            accx[sp][pi[r]][nt * 16 + pn[r]] = acc[nt][r];
#pragma unroll
    for (int r = 0; r < 4; ++r) lx[sp][pi[r]] = accd[r];  // redundant, same value
    __syncthreads();

#pragma unroll
    for (int e = 0; e < 2; ++e) {
        int idx = tid + e * 512;
        int row = idx >> 6, col = idx & 63;
        float num = 0.f, den = 0.f;
#pragma unroll
        for (int s = 0; s < 8; ++s) {
            num += accx[s][row][col];
            den += lx[s][row];
        }
        float o = num / den;
        o = (o > 0.f) ? o : (__expf(o) - 1.f);
        Outb[(size_t)(i0 + row) * HID + hh * 64 + col] = f2bf_rne(o);
    }
}

// ---------------------------------------------------------------------------
// Attention layer 2 (H=1): grid NN/16, 1024 threads = 16 j-splits of 256.
// ---------------------------------------------------------------------------
__global__ __launch_bounds__(1024) void attn_l2(
    const unsigned short* __restrict__ HT,   // [64][4096]
    const unsigned* __restrict__ Adjb,
    const float* __restrict__ ssr, const float* __restrict__ sdr,
    const float* __restrict__ E1d, const float* __restrict__ E2d,
    const float* __restrict__ pI, const float* __restrict__ pN,
    float* __restrict__ Out)                 // [4096][64] f32
{
    __shared__ float accx[16][16][64];
    __shared__ float lx[16][16];
    const int tid = threadIdx.x;
    const int lane = tid & 63, sp = tid >> 6;
    const int m = lane & 15, quad = lane >> 4;
    const int i0 = blockIdx.x * 16;
    int pi[4], pn[4];
    load_probe(pI, pN, lane, pi, pn);

    const float ss_m = ssr[i0 + m];
    const float E1i = __expf(ss_m), E2i = __expf(0.2f * ss_m);
    const float negss = -ss_m;
    const unsigned* mrow = Adjb + (size_t)(i0 + m) * 128;
    const bf16x8 ones = ones_frag();

    f32x4 acc[4] = {};
    f32x4 accd = {};

#pragma unroll
    for (int g = 0; g < 2; ++g) {
        const int jb = sp * 256 + g * 128;
        u32x4 mw = *(const u32x4*)&mrow[jb >> 5];
#pragma unroll
        for (int s = 0; s < 4; ++s) {
            const int kb = jb + s * 32 + quad * 8;
            const unsigned mb = (mw[s] >> (quad * 8)) & 0xffu;
            float4 s0 = *(const float4*)&sdr[kb];
            float4 s1 = *(const float4*)&sdr[kb + 4];
            float4 p0 = *(const float4*)&E1d[kb];
            float4 p1 = *(const float4*)&E1d[kb + 4];
            float4 q0 = *(const float4*)&E2d[kb];
            float4 q1 = *(const float4*)&E2d[kb + 4];
            bf16x8 b[4];
#pragma unroll
            for (int nt = 0; nt < 4; ++nt)
                b[nt] = *(const bf16x8*)&HT[(size_t)(nt * 16 + m) * NN + kb];
            float sdv[8] = {s0.x, s0.y, s0.z, s0.w, s1.x, s1.y, s1.z, s1.w};
            float e1v[8] = {p0.x, p0.y, p0.z, p0.w, p1.x, p1.y, p1.z, p1.w};
            float e2v[8] = {q0.x, q0.y, q0.z, q0.w, q1.x, q1.y, q1.z, q1.w};
            float wv[8];
#pragma unroll
            for (int t = 0; t < 8; ++t) {
                bool pos = sdv[t] >= negss;
                float w = (pos ? E1i : E2i) * (pos ? e1v[t] : e2v[t]);
                wv[t] = ((mb >> t) & 1u) ? w : 0.f;
            }
            bf16x8 av = pack_w(wv);
            accd = __builtin_amdgcn_mfma_f32_16x16x32_bf16(av, ones, accd, 0, 0, 0);
#pragma unroll
            for (int nt = 0; nt < 4; ++nt)
                acc[nt] = __builtin_amdgcn_mfma_f32_16x16x32_bf16(av, b[nt], acc[nt], 0, 0, 0);
        }
    }

#pragma unroll
    for (int nt = 0; nt < 4; ++nt)
#pragma unroll
        for (int r = 0; r < 4; ++r)
            accx[sp][pi[r]][nt * 16 + pn[r]] = acc[nt][r];
#pragma unroll
    for (int r = 0; r < 4; ++r) lx[sp][pi[r]] = accd[r];
    __syncthreads();

    {
        int row = tid >> 6, col = tid & 63;
        float num = 0.f, den = 0.f;
#pragma unroll
        for (int s = 0; s < 16; ++s) {
            num += accx[s][row][col];
            den += lx[s][row];
        }
        Out[(size_t)(i0 + row) * NCLS + col] = num / den;
    }
}

// ---------------------------------------------------------------------------
extern "C" void kernel_launch(void* const* d_in, const int* in_sizes, int n_in,
                              void* d_out, int out_size, void* d_ws, size_t ws_size,
                              hipStream_t stream) {
    const float* x      = (const float*)d_in[0];
    const int*   Adj    = (const int*)d_in[1];
    const float* W1     = (const float*)d_in[2];
    const float* a1_src = (const float*)d_in[3];
    const float* a1_dst = (const float*)d_in[4];
    const float* W2     = (const float*)d_in[5];
    const float* a2_src = (const float*)d_in[6];
    const float* a2_dst = (const float*)d_in[7];
    float* out = (float*)d_out;

    float* ws = (float*)d_ws;
    unsigned short* HT1  = (unsigned short*)ws;                    // [0, 524288)
    unsigned short* HT2  = (unsigned short*)(ws + 524288);         // [524288, 655360)
    unsigned short* h1e  = (unsigned short*)(ws + 655360);         // [655360, 1179648)
    unsigned short* WT1  = (unsigned short*)(ws + 1179648);        // 65536 f
    unsigned short* WT2  = (unsigned short*)(ws + 1245184);        // 8192 f
    unsigned*       Adjb = (unsigned*)(ws + 1253376);              // 524288 u32
    float* s1s  = ws + 1777664;
    float* s1d  = ws + 1794048;
    float* E1d1 = ws + 1810432;
    float* E2d1 = ws + 1826816;
    float* s2s  = ws + 1843200;
    float* s2d  = ws + 1847296;
    float* E1d2 = ws + 1851392;
    float* E2d2 = ws + 1855488;
    float* prI  = ws + 1859584;
    float* prN  = ws + 1859840;

    // Prep
    mfma_probe<<<dim3(1), 64, 0, stream>>>(prI, prN);
    adj_bitmask<<<dim3(16384), 256, 0, stream>>>(Adj, Adjb);
    transpose_cvt<FIN, HID><<<dim3(HID / 32, FIN / 32), 256, 0, stream>>>(W1, WT1);
    transpose_cvt<HID, NCLS><<<dim3(NCLS / 32, HID / 32), 256, 0, stream>>>(W2, WT2);

    // Layer 1
    gemm_head<FIN, false><<<dim3(NH, NN / 16), 256, 0, stream>>>(
        x, WT1, a1_src, a1_dst, prI, prN, HT1, s1s, s1d, E1d1, E2d1);
    attn_l1<<<dim3(NN / 16, NH), 512, 0, stream>>>(
        HT1, Adjb, s1s, s1d, E1d1, E2d1, prI, prN, h1e);

    // Layer 2
    gemm_head<HID, true><<<dim3(1, NN / 16), 256, 0, stream>>>(
        h1e, WT2, a2_src, a2_dst, prI, prN, HT2, s2s, s2d, E1d2, E2d2);
    attn_l2<<<dim3(NN / 16), 1024, 0, stream>>>(
        HT2, Adjb, s2s, s2d, E1d2, E2d2, prI, prN, out);
}

// Round 9
// 235.929 us; speedup vs baseline: 2.7390x; 1.0399x over previous
//
#include <hip/hip_runtime.h>
#include <hip/hip_bf16.h>

// Problem constants
#define NN 4096
#define FIN 512
#define HID 256
#define NH 4
#define DD 64
#define NCLS 64

typedef short bf16x8 __attribute__((ext_vector_type(8)));
typedef float f32x4 __attribute__((ext_vector_type(4)));
typedef unsigned int u32x4 __attribute__((ext_vector_type(4)));

__device__ __forceinline__ unsigned fbits(float x) {
    return __builtin_bit_cast(unsigned, x);
}
__device__ __forceinline__ unsigned short f2bf_rne(float x) {
    unsigned u = fbits(x);
    unsigned r = (u + 0x7fffu + ((u >> 16) & 1u)) >> 16;
    return (unsigned short)r;
}

// pack 8 f32 -> bf16x8 fragment (truncate; R6/R7-verified rounding path)
__device__ __forceinline__ bf16x8 pack_w(const float* wv) {
    u32x4 au;
#pragma unroll
    for (int t = 0; t < 4; ++t)
        au[t] = (fbits(wv[2 * t]) >> 16) | (fbits(wv[2 * t + 1]) & 0xffff0000u);
    return __builtin_bit_cast(bf16x8, au);
}

__device__ __forceinline__ bf16x8 ones_frag() {
    u32x4 au = {0x3f803f80u, 0x3f803f80u, 0x3f803f80u, 0x3f803f80u};
    return __builtin_bit_cast(bf16x8, au);
}

// ---------------------------------------------------------------------------
// Runtime MFMA layout probe (verified R6/R7/R8).
// ---------------------------------------------------------------------------
__global__ __launch_bounds__(64) void mfma_probe(float* __restrict__ pI,
                                                 float* __restrict__ pN) {
    const int l = threadIdx.x;
    const int quad = l >> 4, m = l & 15;
    float xv[8], yv[8];
#pragma unroll
    for (int e = 0; e < 8; ++e) {
        xv[e] = (quad == 0 && e == 0) ? (float)(m + 1) : 0.f;
        yv[e] = (quad == 0 && e == 0) ? 1.f : 0.f;
    }
    bf16x8 x1 = pack_w(xv);
    bf16x8 y1 = pack_w(yv);
#pragma unroll
    for (int e = 0; e < 8; ++e) {
        xv[e] = (quad == 0 && e == 0) ? 1.f : 0.f;
        yv[e] = (quad == 0 && e == 0) ? (float)(m + 1) : 0.f;
    }
    bf16x8 x2 = pack_w(xv);
    bf16x8 y2 = pack_w(yv);
    f32x4 d1 = {};
    f32x4 d2 = {};
    d1 = __builtin_amdgcn_mfma_f32_16x16x32_bf16(x1, y1, d1, 0, 0, 0);
    d2 = __builtin_amdgcn_mfma_f32_16x16x32_bf16(x2, y2, d2, 0, 0, 0);
#pragma unroll
    for (int r = 0; r < 4; ++r) {
        pI[l * 4 + r] = d1[r] - 1.f;
        pN[l * 4 + r] = d2[r] - 1.f;
    }
}

__device__ __forceinline__ void load_probe(const float* pI, const float* pN,
                                           int lane, int* pi, int* pn) {
    float4 a = *(const float4*)&pI[lane * 4];
    float4 b = *(const float4*)&pN[lane * 4];
    float av[4] = {a.x, a.y, a.z, a.w};
    float bv[4] = {b.x, b.y, b.z, b.w};
#pragma unroll
    for (int r = 0; r < 4; ++r) {
        pi[r] = min(15, max(0, (int)av[r]));
        pn[r] = min(15, max(0, (int)bv[r]));
    }
}

// ---------------------------------------------------------------------------
// Adjacency -> bitmask (4 elems/thread, coalesced).
// ---------------------------------------------------------------------------
__global__ __launch_bounds__(256) void adj_bitmask(const int* __restrict__ Adj,
                                                   unsigned* __restrict__ Adjb) {
    const size_t base = (size_t)blockIdx.x * 1024;
    const int tid = threadIdx.x, lane = tid & 63;
#pragma unroll
    for (int c = 0; c < 4; ++c) {
        size_t gid = base + c * 256 + tid;
        int v = Adj[gid];
        unsigned long long bm = __ballot(v > 0);
        if ((lane & 31) == 0)
            Adjb[gid >> 5] = (unsigned)((lane & 32) ? (bm >> 32) : bm);
    }
}

// ---------------------------------------------------------------------------
// Transpose + f32->bf16:  In[R][C] f32 -> OutT[C][R] bf16. (weights only)
// ---------------------------------------------------------------------------
template <int R, int C>
__global__ __launch_bounds__(256) void transpose_cvt(const float* __restrict__ In,
                                                     unsigned short* __restrict__ OutT) {
    __shared__ float t[32][33];
    const int tid = threadIdx.x;
    const int r0 = blockIdx.y * 32, c0 = blockIdx.x * 32;
    const int rl = tid >> 3, cg = tid & 7;
    float4 v = *(const float4*)&In[(size_t)(r0 + rl) * C + c0 + cg * 4];
    t[rl][cg * 4 + 0] = v.x; t[rl][cg * 4 + 1] = v.y;
    t[rl][cg * 4 + 2] = v.z; t[rl][cg * 4 + 3] = v.w;
    __syncthreads();
    const int cl = tid >> 3, rg = tid & 7;
    ushort4 o;
    o.x = f2bf_rne(t[rg * 4 + 0][cl]);
    o.y = f2bf_rne(t[rg * 4 + 1][cl]);
    o.z = f2bf_rne(t[rg * 4 + 2][cl]);
    o.w = f2bf_rne(t[rg * 4 + 3][cl]);
    *(ushort4*)&OutT[(size_t)(c0 + cl) * R + r0 + rg * 4] = o;
}

// ---------------------------------------------------------------------------
// Fused GEMM head: 16x64 tile for head hh, 4-wave k-split. Epilogue emits
// HT (bf16 transposed), raw src score, and EP[j]={exp(sd), exp(0.2 sd)}.
// ---------------------------------------------------------------------------
template <int K, bool ABF>
__global__ __launch_bounds__(256) void gemm_head(
    const void* __restrict__ Ap,
    const unsigned short* __restrict__ WT,      // [H*64][K] bf16
    const float* __restrict__ a_src, const float* __restrict__ a_dst,
    const float* __restrict__ pI, const float* __restrict__ pN,
    unsigned short* __restrict__ HT,            // [H*64][NN] bf16
    float* __restrict__ ssr,                    // [H][NN]
    float* __restrict__ EP)                     // [H][NN][2]
{
    __shared__ float accx[4][16][65];
    __shared__ unsigned short hbf[16][64];
    const int tid = threadIdx.x;
    const int lane = tid & 63, sp = tid >> 6;
    const int m = lane & 15, quad = lane >> 4;
    const int hh = blockIdx.x, i0 = blockIdx.y * 16;
    const int n0 = hh * 64;
    int pi[4], pn[4];
    load_probe(pI, pN, lane, pi, pn);
    f32x4 acc[4] = {};
    constexpr int KS = K / 128;
#pragma unroll
    for (int ks = 0; ks < KS; ++ks) {
        const int kb = sp * (K / 4) + ks * 32 + quad * 8;
        bf16x8 a;
        if (ABF) {
            a = *(const bf16x8*)((const unsigned short*)Ap + (size_t)(i0 + m) * K + kb);
        } else {
            const float* Af = (const float*)Ap + (size_t)(i0 + m) * K + kb;
            float4 a0 = *(const float4*)Af;
            float4 a1 = *(const float4*)(Af + 4);
            float av8[8] = {a0.x, a0.y, a0.z, a0.w, a1.x, a1.y, a1.z, a1.w};
            u32x4 au;
#pragma unroll
            for (int t = 0; t < 4; ++t) {
                unsigned lo = (unsigned)f2bf_rne(av8[2 * t]);
                unsigned hi = (unsigned)f2bf_rne(av8[2 * t + 1]) << 16;
                au[t] = lo | hi;
            }
            a = __builtin_bit_cast(bf16x8, au);
        }
        bf16x8 b[4];
#pragma unroll
        for (int nt = 0; nt < 4; ++nt)
            b[nt] = *(const bf16x8*)&WT[(size_t)(n0 + nt * 16 + m) * K + kb];
#pragma unroll
        for (int nt = 0; nt < 4; ++nt)
            acc[nt] = __builtin_amdgcn_mfma_f32_16x16x32_bf16(a, b[nt], acc[nt], 0, 0, 0);
    }
#pragma unroll
    for (int nt = 0; nt < 4; ++nt)
#pragma unroll
        for (int r = 0; r < 4; ++r)
            accx[sp][pi[r]][nt * 16 + pn[r]] = acc[nt][r];
    __syncthreads();

    const int row = tid >> 4, cg = tid & 15;
    float ps = 0.f, pd = 0.f;
#pragma unroll
    for (int c4 = 0; c4 < 4; ++c4) {
        int col = cg * 4 + c4;
        float val = accx[0][row][col] + accx[1][row][col] +
                    accx[2][row][col] + accx[3][row][col];
        ps += val * a_src[n0 + col];
        pd += val * a_dst[n0 + col];
        hbf[row][col] = f2bf_rne(val);
    }
#pragma unroll
    for (int o = 8; o >= 1; o >>= 1) {
        ps += __shfl_xor(ps, o, 64);
        pd += __shfl_xor(pd, o, 64);
    }
    if (cg == 0) {
        int node = i0 + row;
        ssr[hh * NN + node] = ps;
        EP[(size_t)(hh * NN + node) * 2 + 0] = __expf(pd);
        EP[(size_t)(hh * NN + node) * 2 + 1] = __expf(0.2f * pd);
    }
    __syncthreads();
    const int c = tid >> 2, rq = tid & 3;
    ushort4 o4;
    o4.x = hbf[rq * 4 + 0][c];
    o4.y = hbf[rq * 4 + 1][c];
    o4.z = hbf[rq * 4 + 2][c];
    o4.w = hbf[rq * 4 + 3][c];
    *(ushort4*)&HT[(size_t)(n0 + c) * NN + i0 + rq * 4] = o4;
}

// ---------------------------------------------------------------------------
// Pipelined attention core: NSTEP j-steps of 32 for one wave, starting at
// jbase.  w = mask ? max(E1i*E1j, E2i*E2j) : 0  (== exp(lrelu(ss+sd))).
// EP/B-fragment registers double-buffered (next step's loads issue before
// current step's compute); bitmask u32x4 prefetched one 4-step group ahead.
// ---------------------------------------------------------------------------
template <int NSTEP>
__device__ __forceinline__ void attn_core(
    const unsigned short* __restrict__ htb,  // head's HT base [64][NN]
    const unsigned* __restrict__ mrow_m,     // this lane's bitmask row
    const float* __restrict__ eph,           // head's EP base [NN][2]
    const int jbase, const int m, const int quad,
    const float E1i, const float E2i,
    f32x4* acc, f32x4& accd)
{
    const bf16x8 ones = ones_frag();
    const int wb = jbase >> 5;
    u32x4 mwb[2];
    f32x4 ep[2][4];
    bf16x8 bf[2][4];

    mwb[0] = *(const u32x4*)&mrow_m[wb];
    {
        const int kb = jbase + quad * 8;
        const float* e = eph + 2 * kb;
#pragma unroll
        for (int v = 0; v < 4; ++v) ep[0][v] = *(const f32x4*)(e + 4 * v);
#pragma unroll
        for (int nt = 0; nt < 4; ++nt)
            bf[0][nt] = *(const bf16x8*)&htb[(size_t)(nt * 16 + m) * NN + kb];
    }
#pragma unroll
    for (int s = 0; s < NSTEP; ++s) {
        const int cur = s & 1, nxt = cur ^ 1;
        if (s + 1 < NSTEP) {
            const int kb = jbase + (s + 1) * 32 + quad * 8;
            const float* e = eph + 2 * kb;
#pragma unroll
            for (int v = 0; v < 4; ++v) ep[nxt][v] = *(const f32x4*)(e + 4 * v);
#pragma unroll
            for (int nt = 0; nt < 4; ++nt)
                bf[nxt][nt] = *(const bf16x8*)&htb[(size_t)(nt * 16 + m) * NN + kb];
        }
        if ((s & 3) == 0 && s + 4 < NSTEP)
            mwb[((s >> 2) + 1) & 1] = *(const u32x4*)&mrow_m[wb + (s >> 2) * 4 + 4];

        const unsigned mb = (mwb[(s >> 2) & 1][s & 3] >> (quad * 8)) & 0xffu;
        float wv[8];
#pragma unroll
        for (int t = 0; t < 8; ++t) {
            float e1 = ep[cur][t >> 1][(2 * t) & 3];
            float e2 = ep[cur][t >> 1][(2 * t + 1) & 3];
            float w = fmaxf(E1i * e1, E2i * e2);
            wv[t] = ((mb >> t) & 1u) ? w : 0.f;
        }
        bf16x8 av = pack_w(wv);
        accd = __builtin_amdgcn_mfma_f32_16x16x32_bf16(av, ones, accd, 0, 0, 0);
#pragma unroll
        for (int nt = 0; nt < 4; ++nt)
            acc[nt] = __builtin_amdgcn_mfma_f32_16x16x32_bf16(av, bf[cur][nt], acc[nt], 0, 0, 0);
    }
}

// ---------------------------------------------------------------------------
// Attention layer 1: grid (NN/16, NH), 512 threads = 8 waves = 8 j-splits.
// ---------------------------------------------------------------------------
__global__ __launch_bounds__(512, 4) void attn_l1(
    const unsigned short* __restrict__ HT,   // [256][4096]
    const unsigned* __restrict__ Adjb,
    const float* __restrict__ ssr,           // [4][4096]
    const float* __restrict__ EP,            // [4][4096][2]
    const float* __restrict__ pI, const float* __restrict__ pN,
    unsigned short* __restrict__ Outb)       // [4096][256] bf16 ELU'd
{
    __shared__ float accx[8][16][65];
    __shared__ float lx[8][16];
    const int tid = threadIdx.x;
    const int lane = tid & 63, sp = tid >> 6;
    const int m = lane & 15, quad = lane >> 4;
    const int i0 = blockIdx.x * 16, hh = blockIdx.y;
    int pi[4], pn[4];
    load_probe(pI, pN, lane, pi, pn);

    const float ss_m = ssr[hh * NN + i0 + m];
    const float E1i = __expf(ss_m), E2i = __expf(0.2f * ss_m);
    const unsigned* mrow = Adjb + (size_t)(i0 + m) * 128;
    const unsigned short* htb = HT + (size_t)(hh * 64) * NN;
    const float* eph = EP + (size_t)hh * NN * 2;

    f32x4 acc[4] = {};
    f32x4 accd = {};
    attn_core<16>(htb, mrow, eph, sp * 512, m, quad, E1i, E2i, acc, accd);

#pragma unroll
    for (int nt = 0; nt < 4; ++nt)
#pragma unroll
        for (int r = 0; r < 4; ++r)
            accx[sp][pi[r]][nt * 16 + pn[r]] = acc[nt][r];
#pragma unroll
    for (int r = 0; r < 4; ++r) lx[sp][pi[r]] = accd[r];
    __syncthreads();

#pragma unroll
    for (int e = 0; e < 2; ++e) {
        int idx = tid + e * 512;
        int row = idx >> 6, col = idx & 63;
        float num = 0.f, den = 0.f;
#pragma unroll
        for (int s = 0; s < 8; ++s) {
            num += accx[s][row][col];
            den += lx[s][row];
        }
        float o = num / den;
        o = (o > 0.f) ? o : (__expf(o) - 1.f);
        Outb[(size_t)(i0 + row) * HID + hh * 64 + col] = f2bf_rne(o);
    }
}

// ---------------------------------------------------------------------------
// Attention layer 2 (H=1): grid NN/16, 1024 threads = 16 j-splits of 256.
// ---------------------------------------------------------------------------
__global__ __launch_bounds__(1024, 4) void attn_l2(
    const unsigned short* __restrict__ HT,   // [64][4096]
    const unsigned* __restrict__ Adjb,
    const float* __restrict__ ssr,           // [4096]
    const float* __restrict__ EP,            // [4096][2]
    const float* __restrict__ pI, const float* __restrict__ pN,
    float* __restrict__ Out)                 // [4096][64] f32
{
    __shared__ float accx[16][16][65];
    __shared__ float lx[16][16];
    const int tid = threadIdx.x;
    const int lane = tid & 63, sp = tid >> 6;
    const int m = lane & 15, quad = lane >> 4;
    const int i0 = blockIdx.x * 16;
    int pi[4], pn[4];
    load_probe(pI, pN, lane, pi, pn);

    const float ss_m = ssr[i0 + m];
    const float E1i = __expf(ss_m), E2i = __expf(0.2f * ss_m);
    const unsigned* mrow = Adjb + (size_t)(i0 + m) * 128;

    f32x4 acc[4] = {};
    f32x4 accd = {};
    attn_core<8>(HT, mrow, EP, sp * 256, m, quad, E1i, E2i, acc, accd);

#pragma unroll
    for (int nt = 0; nt < 4; ++nt)
#pragma unroll
        for (int r = 0; r < 4; ++r)
            accx[sp][pi[r]][nt * 16 + pn[r]] = acc[nt][r];
#pragma unroll
    for (int r = 0; r < 4; ++r) lx[sp][pi[r]] = accd[r];
    __syncthreads();

    {
        int row = tid >> 6, col = tid & 63;
        float num = 0.f, den = 0.f;
#pragma unroll
        for (int s = 0; s < 16; ++s) {
            num += accx[s][row][col];
            den += lx[s][row];
        }
        Out[(size_t)(i0 + row) * NCLS + col] = num / den;
    }
}

// ---------------------------------------------------------------------------
extern "C" void kernel_launch(void* const* d_in, const int* in_sizes, int n_in,
                              void* d_out, int out_size, void* d_ws, size_t ws_size,
                              hipStream_t stream) {
    const float* x      = (const float*)d_in[0];
    const int*   Adj    = (const int*)d_in[1];
    const float* W1     = (const float*)d_in[2];
    const float* a1_src = (const float*)d_in[3];
    const float* a1_dst = (const float*)d_in[4];
    const float* W2     = (const float*)d_in[5];
    const float* a2_src = (const float*)d_in[6];
    const float* a2_dst = (const float*)d_in[7];
    float* out = (float*)d_out;

    float* ws = (float*)d_ws;
    unsigned short* HT1  = (unsigned short*)ws;                    // 524288 f
    unsigned short* HT2  = (unsigned short*)(ws + 524288);         // 131072 f
    unsigned short* h1e  = (unsigned short*)(ws + 655360);         // 524288 f
    unsigned short* WT1  = (unsigned short*)(ws + 1179648);        // 65536 f
    unsigned short* WT2  = (unsigned short*)(ws + 1245184);        // 8192 f
    unsigned*       Adjb = (unsigned*)(ws + 1253376);              // 524288 u32
    float* s1s = ws + 1777664;   // 16384
    float* EP1 = ws + 1794048;   // 32768
    float* s2s = ws + 1826816;   // 4096
    float* EP2 = ws + 1830912;   // 8192
    float* prI = ws + 1839104;   // 256
    float* prN = ws + 1839360;   // 256

    // Prep
    mfma_probe<<<dim3(1), 64, 0, stream>>>(prI, prN);
    adj_bitmask<<<dim3(16384), 256, 0, stream>>>(Adj, Adjb);
    transpose_cvt<FIN, HID><<<dim3(HID / 32, FIN / 32), 256, 0, stream>>>(W1, WT1);
    transpose_cvt<HID, NCLS><<<dim3(NCLS / 32, HID / 32), 256, 0, stream>>>(W2, WT2);

    // Layer 1
    gemm_head<FIN, false><<<dim3(NH, NN / 16), 256, 0, stream>>>(
        x, WT1, a1_src, a1_dst, prI, prN, HT1, s1s, EP1);
    attn_l1<<<dim3(NN / 16, NH), 512, 0, stream>>>(
        HT1, Adjb, s1s, EP1, prI, prN, h1e);

    // Layer 2
    gemm_head<HID, true><<<dim3(1, NN / 16), 256, 0, stream>>>(
        h1e, WT2, a2_src, a2_dst, prI, prN, HT2, s2s, EP2);
    attn_l2<<<dim3(NN / 16), 1024, 0, stream>>>(
        HT2, Adjb, s2s, EP2, prI, prN, out);
}

// Round 10
// 190.686 us; speedup vs baseline: 3.3889x; 1.2373x over previous
//
#include <hip/hip_runtime.h>
#include <hip/hip_bf16.h>

// Problem constants
#define NN 4096
#define FIN 512
#define HID 256
#define NH 4
#define DD 64
#define NCLS 64

typedef short bf16x8 __attribute__((ext_vector_type(8)));
typedef float f32x4 __attribute__((ext_vector_type(4)));
typedef unsigned int u32x4 __attribute__((ext_vector_type(4)));

__device__ __forceinline__ unsigned fbits(float x) {
    return __builtin_bit_cast(unsigned, x);
}
__device__ __forceinline__ float fbitsf(unsigned u) {
    return __builtin_bit_cast(float, u);
}
__device__ __forceinline__ unsigned short f2bf_rne(float x) {
    unsigned u = fbits(x);
    unsigned r = (u + 0x7fffu + ((u >> 16) & 1u)) >> 16;
    return (unsigned short)r;
}

// pack 8 f32 -> bf16x8 fragment (truncate) + accumulate the SAME rounded
// values into lpart (denominator consistency). R6-verified path.
__device__ __forceinline__ bf16x8 pack_w(const float* wv, float& lpart) {
    u32x4 au;
#pragma unroll
    for (int t = 0; t < 4; ++t) {
        unsigned lo = fbits(wv[2 * t]) >> 16;
        unsigned hi = fbits(wv[2 * t + 1]) & 0xffff0000u;
        au[t] = lo | hi;
        lpart += fbitsf(lo << 16) + fbitsf(hi);
    }
    return __builtin_bit_cast(bf16x8, au);
}

// ---------------------------------------------------------------------------
// Runtime MFMA layout probe (verified R6-R9).
// ---------------------------------------------------------------------------
__global__ __launch_bounds__(64) void mfma_probe(float* __restrict__ pI,
                                                 float* __restrict__ pN) {
    const int l = threadIdx.x;
    const int quad = l >> 4, m = l & 15;
    float dummy = 0.f;
    float xv[8], yv[8];
#pragma unroll
    for (int e = 0; e < 8; ++e) {
        xv[e] = (quad == 0 && e == 0) ? (float)(m + 1) : 0.f;
        yv[e] = (quad == 0 && e == 0) ? 1.f : 0.f;
    }
    bf16x8 x1 = pack_w(xv, dummy);
    bf16x8 y1 = pack_w(yv, dummy);
#pragma unroll
    for (int e = 0; e < 8; ++e) {
        xv[e] = (quad == 0 && e == 0) ? 1.f : 0.f;
        yv[e] = (quad == 0 && e == 0) ? (float)(m + 1) : 0.f;
    }
    bf16x8 x2 = pack_w(xv, dummy);
    bf16x8 y2 = pack_w(yv, dummy);
    f32x4 d1 = {};
    f32x4 d2 = {};
    d1 = __builtin_amdgcn_mfma_f32_16x16x32_bf16(x1, y1, d1, 0, 0, 0);
    d2 = __builtin_amdgcn_mfma_f32_16x16x32_bf16(x2, y2, d2, 0, 0, 0);
#pragma unroll
    for (int r = 0; r < 4; ++r) {
        pI[l * 4 + r] = d1[r] - 1.f;
        pN[l * 4 + r] = d2[r] - 1.f;
    }
}

__device__ __forceinline__ void load_probe(const float* pI, const float* pN,
                                           int lane, int* pi, int* pn) {
    float4 a = *(const float4*)&pI[lane * 4];
    float4 b = *(const float4*)&pN[lane * 4];
    float av[4] = {a.x, a.y, a.z, a.w};
    float bv[4] = {b.x, b.y, b.z, b.w};
#pragma unroll
    for (int r = 0; r < 4; ++r) {
        pi[r] = min(15, max(0, (int)av[r]));
        pn[r] = min(15, max(0, (int)bv[r]));
    }
}

// ---------------------------------------------------------------------------
// Adjacency -> bitmask (4 elems/thread, coalesced).
// ---------------------------------------------------------------------------
__global__ __launch_bounds__(256) void adj_bitmask(const int* __restrict__ Adj,
                                                   unsigned* __restrict__ Adjb) {
    const size_t base = (size_t)blockIdx.x * 1024;
    const int tid = threadIdx.x, lane = tid & 63;
#pragma unroll
    for (int c = 0; c < 4; ++c) {
        size_t gid = base + c * 256 + tid;
        int v = Adj[gid];
        unsigned long long bm = __ballot(v > 0);
        if ((lane & 31) == 0)
            Adjb[gid >> 5] = (unsigned)((lane & 32) ? (bm >> 32) : bm);
    }
}

// ---------------------------------------------------------------------------
// Transpose + f32->bf16:  In[R][C] f32 -> OutT[C][R] bf16. (weights only)
// ---------------------------------------------------------------------------
template <int R, int C>
__global__ __launch_bounds__(256) void transpose_cvt(const float* __restrict__ In,
                                                     unsigned short* __restrict__ OutT) {
    __shared__ float t[32][33];
    const int tid = threadIdx.x;
    const int r0 = blockIdx.y * 32, c0 = blockIdx.x * 32;
    const int rl = tid >> 3, cg = tid & 7;
    float4 v = *(const float4*)&In[(size_t)(r0 + rl) * C + c0 + cg * 4];
    t[rl][cg * 4 + 0] = v.x; t[rl][cg * 4 + 1] = v.y;
    t[rl][cg * 4 + 2] = v.z; t[rl][cg * 4 + 3] = v.w;
    __syncthreads();
    const int cl = tid >> 3, rg = tid & 7;
    ushort4 o;
    o.x = f2bf_rne(t[rg * 4 + 0][cl]);
    o.y = f2bf_rne(t[rg * 4 + 1][cl]);
    o.z = f2bf_rne(t[rg * 4 + 2][cl]);
    o.w = f2bf_rne(t[rg * 4 + 3][cl]);
    *(ushort4*)&OutT[(size_t)(c0 + cl) * R + r0 + rg * 4] = o;
}

// ---------------------------------------------------------------------------
// Fused GEMM head (unchanged from R9): 16x64 tile, 4-wave k-split; emits
// HT (bf16 transposed), src score, EP[j]={exp(sd), exp(0.2 sd)}.
// ---------------------------------------------------------------------------
template <int K, bool ABF>
__global__ __launch_bounds__(256) void gemm_head(
    const void* __restrict__ Ap,
    const unsigned short* __restrict__ WT,
    const float* __restrict__ a_src, const float* __restrict__ a_dst,
    const float* __restrict__ pI, const float* __restrict__ pN,
    unsigned short* __restrict__ HT,
    float* __restrict__ ssr,
    float* __restrict__ EP)
{
    __shared__ float accx[4][16][65];
    __shared__ unsigned short hbf[16][64];
    const int tid = threadIdx.x;
    const int lane = tid & 63, sp = tid >> 6;
    const int m = lane & 15, quad = lane >> 4;
    const int hh = blockIdx.x, i0 = blockIdx.y * 16;
    const int n0 = hh * 64;
    int pi[4], pn[4];
    load_probe(pI, pN, lane, pi, pn);
    f32x4 acc[4] = {};
    constexpr int KS = K / 128;
#pragma unroll
    for (int ks = 0; ks < KS; ++ks) {
        const int kb = sp * (K / 4) + ks * 32 + quad * 8;
        bf16x8 a;
        if (ABF) {
            a = *(const bf16x8*)((const unsigned short*)Ap + (size_t)(i0 + m) * K + kb);
        } else {
            const float* Af = (const float*)Ap + (size_t)(i0 + m) * K + kb;
            float4 a0 = *(const float4*)Af;
            float4 a1 = *(const float4*)(Af + 4);
            float av8[8] = {a0.x, a0.y, a0.z, a0.w, a1.x, a1.y, a1.z, a1.w};
            u32x4 au;
#pragma unroll
            for (int t = 0; t < 4; ++t) {
                unsigned lo = (unsigned)f2bf_rne(av8[2 * t]);
                unsigned hi = (unsigned)f2bf_rne(av8[2 * t + 1]) << 16;
                au[t] = lo | hi;
            }
            a = __builtin_bit_cast(bf16x8, au);
        }
        bf16x8 b[4];
#pragma unroll
        for (int nt = 0; nt < 4; ++nt)
            b[nt] = *(const bf16x8*)&WT[(size_t)(n0 + nt * 16 + m) * K + kb];
#pragma unroll
        for (int nt = 0; nt < 4; ++nt)
            acc[nt] = __builtin_amdgcn_mfma_f32_16x16x32_bf16(a, b[nt], acc[nt], 0, 0, 0);
    }
#pragma unroll
    for (int nt = 0; nt < 4; ++nt)
#pragma unroll
        for (int r = 0; r < 4; ++r)
            accx[sp][pi[r]][nt * 16 + pn[r]] = acc[nt][r];
    __syncthreads();

    const int row = tid >> 4, cg = tid & 15;
    float ps = 0.f, pd = 0.f;
#pragma unroll
    for (int c4 = 0; c4 < 4; ++c4) {
        int col = cg * 4 + c4;
        float val = accx[0][row][col] + accx[1][row][col] +
                    accx[2][row][col] + accx[3][row][col];
        ps += val * a_src[n0 + col];
        pd += val * a_dst[n0 + col];
        hbf[row][col] = f2bf_rne(val);
    }
#pragma unroll
    for (int o = 8; o >= 1; o >>= 1) {
        ps += __shfl_xor(ps, o, 64);
        pd += __shfl_xor(pd, o, 64);
    }
    if (cg == 0) {
        int node = i0 + row;
        ssr[hh * NN + node] = ps;
        EP[(size_t)(hh * NN + node) * 2 + 0] = __expf(pd);
        EP[(size_t)(hh * NN + node) * 2 + 1] = __expf(0.2f * pd);
    }
    __syncthreads();
    const int c = tid >> 2, rq = tid & 3;
    ushort4 o4;
    o4.x = hbf[rq * 4 + 0][c];
    o4.y = hbf[rq * 4 + 1][c];
    o4.z = hbf[rq * 4 + 2][c];
    o4.w = hbf[rq * 4 + 3][c];
    *(ushort4*)&HT[(size_t)(n0 + c) * NN + i0 + rq * 4] = o4;
}

// ---------------------------------------------------------------------------
// Multi-i-tile pipelined attention core.  One wave: IT i-tiles (16 rows
// each) x NSTEP j-steps of 32.  Per step the 8 loads (4 EP f32x4 + 4 HT
// bf16x8) are shared across all IT tiles -> ~400 cyc compute per 128 B
// loaded; 1-step lookahead covers L2 latency.  Bitmasks double-buffered
// per 4-step group.  w = mask ? max(E1i*E1j, E2i*E2j) : 0.
// ---------------------------------------------------------------------------
template <int IT, int NSTEP>
__device__ __forceinline__ void attn_core_mt(
    const unsigned short* __restrict__ htb,  // head slice [64][NN]
    const unsigned* __restrict__ Adjb,
    const float* __restrict__ ssh,           // head ss base [NN]
    const float* __restrict__ eph,           // head EP base [NN][2]
    const int i0, const int jbase, const int m, const int quad,
    f32x4 (&acc)[IT][4], float (&lpart)[IT])
{
    const unsigned* mrow[IT];
    float E1i[IT], E2i[IT];
#pragma unroll
    for (int t = 0; t < IT; ++t) {
        float ss = ssh[i0 + t * 16 + m];
        E1i[t] = __expf(ss);
        E2i[t] = __expf(0.2f * ss);
        mrow[t] = Adjb + (size_t)(i0 + t * 16 + m) * 128 + (jbase >> 5);
        lpart[t] = 0.f;
    }
    u32x4 mwb[2][IT];
    f32x4 ep[2][4];
    bf16x8 bf[2][4];
#pragma unroll
    for (int t = 0; t < IT; ++t) mwb[0][t] = *(const u32x4*)mrow[t];
    {
        const int kb = jbase + quad * 8;
        const float* e = eph + 2 * kb;
#pragma unroll
        for (int v = 0; v < 4; ++v) ep[0][v] = *(const f32x4*)(e + 4 * v);
#pragma unroll
        for (int nt = 0; nt < 4; ++nt)
            bf[0][nt] = *(const bf16x8*)&htb[(size_t)(nt * 16 + m) * NN + kb];
    }
#pragma unroll
    for (int s = 0; s < NSTEP; ++s) {
        const int cur = s & 1, nxt = cur ^ 1;
        if (s + 1 < NSTEP) {
            const int kb = jbase + (s + 1) * 32 + quad * 8;
            const float* e = eph + 2 * kb;
#pragma unroll
            for (int v = 0; v < 4; ++v) ep[nxt][v] = *(const f32x4*)(e + 4 * v);
#pragma unroll
            for (int nt = 0; nt < 4; ++nt)
                bf[nxt][nt] = *(const bf16x8*)&htb[(size_t)(nt * 16 + m) * NN + kb];
        }
        if ((s & 3) == 0 && s + 4 < NSTEP) {
#pragma unroll
            for (int t = 0; t < IT; ++t)
                mwb[((s >> 2) + 1) & 1][t] =
                    *(const u32x4*)(mrow[t] + (s >> 2) * 4 + 4);
        }
#pragma unroll
        for (int t = 0; t < IT; ++t) {
            const unsigned mb = (mwb[(s >> 2) & 1][t][s & 3] >> (quad * 8)) & 0xffu;
            float wv[8];
#pragma unroll
            for (int u = 0; u < 8; ++u) {
                float e1 = ep[cur][u >> 1][(2 * u) & 3];
                float e2 = ep[cur][u >> 1][(2 * u + 1) & 3];
                float w = fmaxf(E1i[t] * e1, E2i[t] * e2);
                wv[u] = ((mb >> u) & 1u) ? w : 0.f;
            }
            bf16x8 av = pack_w(wv, lpart[t]);
#pragma unroll
            for (int nt = 0; nt < 4; ++nt)
                acc[t][nt] = __builtin_amdgcn_mfma_f32_16x16x32_bf16(
                    av, bf[cur][nt], acc[t][nt], 0, 0, 0);
        }
    }
}

// ---------------------------------------------------------------------------
// Attention layer 1: grid (NN/64, NH), 512 threads = 8 waves = 8 j-splits
// of 512; each wave handles 4 i-tiles (64 rows).
// ---------------------------------------------------------------------------
__global__ __launch_bounds__(512, 2) void attn_l1(
    const unsigned short* __restrict__ HT,   // [256][4096]
    const unsigned* __restrict__ Adjb,
    const float* __restrict__ ssr,           // [4][4096]
    const float* __restrict__ EP,            // [4][4096][2]
    const float* __restrict__ pI, const float* __restrict__ pN,
    unsigned short* __restrict__ Outb)       // [4096][256] bf16 ELU'd
{
    __shared__ float accx[8][16][65];
    __shared__ float lx[8][16];
    const int tid = threadIdx.x;
    const int lane = tid & 63, sp = tid >> 6;
    const int m = lane & 15, quad = lane >> 4;
    const int i0 = blockIdx.x * 64, hh = blockIdx.y;
    int pi[4], pn[4];
    load_probe(pI, pN, lane, pi, pn);

    const unsigned short* htb = HT + (size_t)(hh * 64) * NN;
    const float* eph = EP + (size_t)hh * NN * 2;
    const float* ssh = ssr + hh * NN;

    f32x4 acc[4][4] = {};
    float lp[4];
    attn_core_mt<4, 16>(htb, Adjb, ssh, eph, i0, sp * 512, m, quad, acc, lp);

#pragma unroll
    for (int t = 0; t < 4; ++t) {
        lp[t] += __shfl_xor(lp[t], 16, 64);
        lp[t] += __shfl_xor(lp[t], 32, 64);
    }

#pragma unroll
    for (int t = 0; t < 4; ++t) {
        if (t) __syncthreads();
#pragma unroll
        for (int nt = 0; nt < 4; ++nt)
#pragma unroll
            for (int r = 0; r < 4; ++r)
                accx[sp][pi[r]][nt * 16 + pn[r]] = acc[t][nt][r];
        if (quad == 0) lx[sp][m] = lp[t];
        __syncthreads();
#pragma unroll
        for (int e = 0; e < 2; ++e) {
            int idx = tid + e * 512;
            int row = idx >> 6, col = idx & 63;
            float num = 0.f, den = 0.f;
#pragma unroll
            for (int s = 0; s < 8; ++s) {
                num += accx[s][row][col];
                den += lx[s][row];
            }
            float o = num / den;
            o = (o > 0.f) ? o : (__expf(o) - 1.f);
            Outb[(size_t)(i0 + t * 16 + row) * HID + hh * 64 + col] = f2bf_rne(o);
        }
    }
}

// ---------------------------------------------------------------------------
// Attention layer 2 (H=1): grid NN/32, 512 threads = 8 j-splits of 512;
// 2 i-tiles per wave.
// ---------------------------------------------------------------------------
__global__ __launch_bounds__(512, 2) void attn_l2(
    const unsigned short* __restrict__ HT,   // [64][4096]
    const unsigned* __restrict__ Adjb,
    const float* __restrict__ ssr,           // [4096]
    const float* __restrict__ EP,            // [4096][2]
    const float* __restrict__ pI, const float* __restrict__ pN,
    float* __restrict__ Out)                 // [4096][64] f32
{
    __shared__ float accx[8][16][65];
    __shared__ float lx[8][16];
    const int tid = threadIdx.x;
    const int lane = tid & 63, sp = tid >> 6;
    const int m = lane & 15, quad = lane >> 4;
    const int i0 = blockIdx.x * 32;
    int pi[4], pn[4];
    load_probe(pI, pN, lane, pi, pn);

    f32x4 acc[2][4] = {};
    float lp[2];
    attn_core_mt<2, 16>(HT, Adjb, ssr, EP, i0, sp * 512, m, quad, acc, lp);

#pragma unroll
    for (int t = 0; t < 2; ++t) {
        lp[t] += __shfl_xor(lp[t], 16, 64);
        lp[t] += __shfl_xor(lp[t], 32, 64);
    }

#pragma unroll
    for (int t = 0; t < 2; ++t) {
        if (t) __syncthreads();
#pragma unroll
        for (int nt = 0; nt < 4; ++nt)
#pragma unroll
            for (int r = 0; r < 4; ++r)
                accx[sp][pi[r]][nt * 16 + pn[r]] = acc[t][nt][r];
        if (quad == 0) lx[sp][m] = lp[t];
        __syncthreads();
#pragma unroll
        for (int e = 0; e < 2; ++e) {
            int idx = tid + e * 512;
            int row = idx >> 6, col = idx & 63;
            float num = 0.f, den = 0.f;
#pragma unroll
            for (int s = 0; s < 8; ++s) {
                num += accx[s][row][col];
                den += lx[s][row];
            }
            Out[(size_t)(i0 + t * 16 + row) * NCLS + col] = num / den;
        }
    }
}

// ---------------------------------------------------------------------------
extern "C" void kernel_launch(void* const* d_in, const int* in_sizes, int n_in,
                              void* d_out, int out_size, void* d_ws, size_t ws_size,
                              hipStream_t stream) {
    const float* x      = (const float*)d_in[0];
    const int*   Adj    = (const int*)d_in[1];
    const float* W1     = (const float*)d_in[2];
    const float* a1_src = (const float*)d_in[3];
    const float* a1_dst = (const float*)d_in[4];
    const float* W2     = (const float*)d_in[5];
    const float* a2_src = (const float*)d_in[6];
    const float* a2_dst = (const float*)d_in[7];
    float* out = (float*)d_out;

    float* ws = (float*)d_ws;
    unsigned short* HT1  = (unsigned short*)ws;                    // 524288 f
    unsigned short* HT2  = (unsigned short*)(ws + 524288);         // 131072 f
    unsigned short* h1e  = (unsigned short*)(ws + 655360);         // 524288 f
    unsigned short* WT1  = (unsigned short*)(ws + 1179648);        // 65536 f
    unsigned short* WT2  = (unsigned short*)(ws + 1245184);        // 8192 f
    unsigned*       Adjb = (unsigned*)(ws + 1253376);              // 524288 u32
    float* s1s = ws + 1777664;   // 16384
    float* EP1 = ws + 1794048;   // 32768
    float* s2s = ws + 1826816;   // 4096
    float* EP2 = ws + 1830912;   // 8192
    float* prI = ws + 1839104;   // 256
    float* prN = ws + 1839360;   // 256

    // Prep
    mfma_probe<<<dim3(1), 64, 0, stream>>>(prI, prN);
    adj_bitmask<<<dim3(16384), 256, 0, stream>>>(Adj, Adjb);
    transpose_cvt<FIN, HID><<<dim3(HID / 32, FIN / 32), 256, 0, stream>>>(W1, WT1);
    transpose_cvt<HID, NCLS><<<dim3(NCLS / 32, HID / 32), 256, 0, stream>>>(W2, WT2);

    // Layer 1
    gemm_head<FIN, false><<<dim3(NH, NN / 16), 256, 0, stream>>>(
        x, WT1, a1_src, a1_dst, prI, prN, HT1, s1s, EP1);
    attn_l1<<<dim3(NN / 64, NH), 512, 0, stream>>>(
        HT1, Adjb, s1s, EP1, prI, prN, h1e);

    // Layer 2
    gemm_head<HID, true><<<dim3(1, NN / 16), 256, 0, stream>>>(
        h1e, WT2, a2_src, a2_dst, prI, prN, HT2, s2s, EP2);
    attn_l2<<<dim3(NN / 32), 512, 0, stream>>>(
        HT2, Adjb, s2s, EP2, prI, prN, out);
}